// Round 1
// baseline (7592.174 us; speedup 1.0000x reference)
//
#include <hip/hip_runtime.h>
#include <math.h>

#define BB 2
#define NVIEW 6
#define BN 12
#define CIN 64
#define HH 48
#define WW 48
#define PP (HH*WW)        // 2304
#define OC 192
#define HPA 192
#define NRATES 3
#define HIDP 64
#define KHW 16
#define PK 256

// ---- workspace layout (float elements) ----
#define OFF_WEFF 0
#define SZ_WEFF (NRATES*OC*CIN*9)          // 331776
#define OFF_BEFF (OFF_WEFF + SZ_WEFF)
#define SZ_BEFF 256
#define OFF_HID (OFF_BEFF + SZ_BEFF)
#define SZ_HID (BN*OC*PP)                  // 5308416
#define OFF_QKV (OFF_HID + SZ_HID)
#define SZ_QKV (BN*OC*PP)
#define OFF_K (OFF_QKV + SZ_QKV)
#define SZ_K (BN*HIDP*PK)                  // 196608
#define OFF_V (OFF_K + SZ_K)
#define SZ_V (BN*HIDP*PK)
#define OFF_ATTN (OFF_V + SZ_V)
#define SZ_ATTN (BN*HIDP*PP)               // 1769472

// K1: fold pa_cw1 (192x576) into three effective dilated convs 64->192
__global__ void k_fold(const float* __restrict__ cw1, const float* __restrict__ cb1,
                       const float* __restrict__ w1, const float* __restrict__ b1,
                       const float* __restrict__ w2, const float* __restrict__ b2,
                       const float* __restrict__ w3, const float* __restrict__ b3,
                       float* __restrict__ weff, float* __restrict__ beff) {
    int r = blockIdx.x / OC;
    int o = blockIdx.x % OC;
    int t = threadIdx.x;                   // i*9 + tap, 0..575
    const float* w = (r==0) ? w1 : (r==1) ? w2 : w3;
    float acc = 0.f;
    for (int c = 0; c < HPA; ++c)
        acc += cw1[o*(HPA*NRATES) + r*HPA + c] * w[c*(CIN*9) + t];
    weff[(r*OC + o)*(CIN*9) + t] = acc;
    if (r == 0 && t == 0) {
        float bacc = cb1[o];
        for (int rr = 0; rr < NRATES; ++rr) {
            const float* bb = (rr==0)?b1:(rr==1)?b2:b3;
            for (int c = 0; c < HPA; ++c)
                bacc += cw1[o*(HPA*NRATES) + rr*HPA + c] * bb[c];
        }
        beff[o] = bacc;
    }
}

// K2: hidden = relu( sum_r dilconv(x, Weff_r) + beff )   [BN,192,48,48]
__global__ __launch_bounds__(256) void k_hidden(const float* __restrict__ x,
        const float* __restrict__ weff, const float* __restrict__ beff,
        float* __restrict__ hid) {
    int bx = blockIdx.x;
    int pb = bx % 9; bx /= 9;
    int ocg = bx % 24; bx /= 24;
    int bn = bx;
    int p = pb*256 + threadIdx.x;
    int y = p / WW, x0 = p % WW;
    int oc0 = ocg*8;
    float acc[8] = {0,0,0,0,0,0,0,0};
    const float* xb = x + (size_t)bn*CIN*PP;
    for (int r = 0; r < 3; ++r) {
        int d = r+1;
        const float* wb = weff + (size_t)(r*OC + oc0)*(CIN*9);
        for (int ic = 0; ic < CIN; ++ic) {
            const float* xp = xb + ic*PP;
            const float* wi = wb + ic*9;
            #pragma unroll
            for (int ky = 0; ky < 3; ++ky) {
                int yy = y + (ky-1)*d;
                if (yy < 0 || yy >= HH) continue;
                #pragma unroll
                for (int kx = 0; kx < 3; ++kx) {
                    int xc = x0 + (kx-1)*d;
                    if (xc < 0 || xc >= WW) continue;
                    float xv = xp[yy*WW + xc];
                    #pragma unroll
                    for (int j = 0; j < 8; ++j)
                        acc[j] += wi[j*(CIN*9) + ky*3+kx] * xv;
                }
            }
        }
    }
    float* hb = hid + (size_t)bn*OC*PP;
    #pragma unroll
    for (int j = 0; j < 8; ++j)
        hb[(oc0+j)*PP + p] = fmaxf(acc[j] + beff[oc0+j], 0.f);
}

// K3: qkv = relu( cw2 @ hidden + cb2 )   [BN,192,2304]
__global__ __launch_bounds__(256) void k_qkv(const float* __restrict__ hid,
        const float* __restrict__ cw2, const float* __restrict__ cb2,
        float* __restrict__ qkv) {
    int bx = blockIdx.x;
    int pb = bx % 9; bx /= 9;
    int ocg = bx % 24; bx /= 24;
    int bn = bx;
    int p = pb*256 + threadIdx.x;
    int oc0 = ocg*8;
    float acc[8] = {0,0,0,0,0,0,0,0};
    const float* hb = hid + (size_t)bn*OC*PP;
    for (int c = 0; c < OC; ++c) {
        float hv = hb[c*PP + p];
        #pragma unroll
        for (int j = 0; j < 8; ++j)
            acc[j] += cw2[(oc0+j)*OC + c] * hv;
    }
    float* qb = qkv + (size_t)bn*OC*PP;
    #pragma unroll
    for (int j = 0; j < 8; ++j)
        qb[(oc0+j)*PP + p] = fmaxf(acc[j] + cb2[oc0+j], 0.f);
}

// K4: K = avgpool3(relu(conv3x3(xk)+b)), V = same(xv)/9   [BN,64,256]
__global__ __launch_bounds__(256) void k_tokv(const float* __restrict__ qkv,
        const float* __restrict__ kvw, const float* __restrict__ kvb,
        float* __restrict__ kdst, float* __restrict__ vdst) {
    int g = blockIdx.x*256 + threadIdx.x;
    int dg = g % 8; g /= 8;
    int pp = g % PK; g /= PK;
    int kv = g % 2; g /= 2;
    int bn = g;
    int qy = pp / KHW, qx = pp % KHW;
    int d0 = dg*8;
    const float* src = qkv + (size_t)bn*OC*PP + (size_t)(kv+1)*HIDP*PP;
    float acc[8] = {0,0,0,0,0,0,0,0};
    for (int sy = 0; sy < 3; ++sy)
    for (int sx = 0; sx < 3; ++sx) {
        int py = qy*3+sy, px = qx*3+sx;
        float cacc[8] = {0,0,0,0,0,0,0,0};
        for (int ic = 0; ic < HIDP; ++ic) {
            const float* sp = src + ic*PP;
            #pragma unroll
            for (int ky = 0; ky < 3; ++ky) {
                int yy = py+ky-1; if (yy<0||yy>=HH) continue;
                #pragma unroll
                for (int kx = 0; kx < 3; ++kx) {
                    int xc = px+kx-1; if (xc<0||xc>=WW) continue;
                    float xv = sp[yy*WW+xc];
                    #pragma unroll
                    for (int j=0;j<8;++j)
                        cacc[j] += kvw[((d0+j)*HIDP + ic)*9 + ky*3+kx] * xv;
                }
            }
        }
        #pragma unroll
        for (int j=0;j<8;++j)
            acc[j] += fmaxf(cacc[j] + kvb[d0+j], 0.f);
    }
    float sc = (kv==0) ? (1.f/9.f) : (1.f/81.f);
    float* dst = (kv==0) ? kdst : vdst;
    #pragma unroll
    for (int j=0;j<8;++j)
        dst[(size_t)bn*HIDP*PK + (d0+j)*PK + pp] = acc[j]*sc;
}

// K5: leave-one-out sigmoid attention; accumulate into attn via atomics.
__global__ __launch_bounds__(256) void k_attn(const float* __restrict__ qkv,
        const float* __restrict__ kbuf, const float* __restrict__ vbuf,
        float* __restrict__ attn) {
    int bx = blockIdx.x;
    int pb = bx % 9; bx /= 9;
    int ks = bx % 2; bx /= 2;
    int m  = bx % NVIEW; bx /= NVIEW;
    int n  = bx % NVIEW; bx /= NVIEW;
    int b  = bx;
    if (m == n) return;
    int p = pb*256 + threadIdx.x;
    int bnq = b*NVIEW + n, bnk = b*NVIEW + m;
    const float* qb = qkv + (size_t)bnq*OC*PP;   // xq = channels 0..63
    float q[64];
    #pragma unroll
    for (int d = 0; d < 64; ++d) q[d] = qb[d*PP + p];
    const float* kb = kbuf + (size_t)bnk*HIDP*PK;
    const float* vb = vbuf + (size_t)bnk*HIDP*PK;
    float acc[64];
    #pragma unroll
    for (int d=0; d<64; ++d) acc[d]=0.f;
    for (int k = ks*128; k < ks*128+128; ++k) {
        float dot = 0.f;
        #pragma unroll
        for (int d=0; d<64; ++d) dot += q[d]*kb[d*PK + k];
        float a = 1.f/(1.f + __expf(-dot*0.125f));
        #pragma unroll
        for (int d=0; d<64; ++d) acc[d] += a * vb[d*PK + k];
    }
    float* ab = attn + (size_t)bnq*HIDP*PP;
    #pragma unroll
    for (int d=0; d<64; ++d) atomicAdd(&ab[d*PP + p], acc[d]);
}

// K6: out = relu(W2 relu(W1 relu(attn + scale*xv) + b1) + b2)
__global__ __launch_bounds__(256) void k_out(const float* __restrict__ attn,
        const float* __restrict__ qkv, const float* __restrict__ scales,
        const float* __restrict__ w1, const float* __restrict__ b1,
        const float* __restrict__ w2, const float* __restrict__ b2,
        float* __restrict__ out) {
    int bx = blockIdx.x;
    int pb = bx % 9; int bn = bx / 9;
    int p = pb*256 + threadIdx.x;
    int n = bn % NVIEW;
    float sc = scales[n];
    const float* ab = attn + (size_t)bn*HIDP*PP;
    const float* xvb = qkv + (size_t)bn*OC*PP + (size_t)2*HIDP*PP;
    float res[64];
    #pragma unroll
    for (int i=0;i<64;++i) res[i] = fmaxf(ab[i*PP+p] + sc*xvb[i*PP+p], 0.f);
    float t[64];
    #pragma unroll
    for (int o=0;o<64;++o) {
        float a = b1[o];
        #pragma unroll
        for (int i=0;i<64;++i) a += w1[o*64+i]*res[i];
        t[o] = fmaxf(a, 0.f);
    }
    float* ob = out + (size_t)bn*HIDP*PP;
    #pragma unroll
    for (int o=0;o<64;++o) {
        float a = b2[o];
        #pragma unroll
        for (int i=0;i<64;++i) a += w2[o*64+i]*t[i];
        ob[o*PP+p] = fmaxf(a, 0.f);
    }
}

extern "C" void kernel_launch(void* const* d_in, const int* in_sizes, int n_in,
                              void* d_out, int out_size, void* d_ws, size_t ws_size,
                              hipStream_t stream) {
    (void)in_sizes; (void)n_in; (void)out_size; (void)ws_size;
    const float* x      = (const float*)d_in[0];
    const float* pa_w1  = (const float*)d_in[1];
    const float* pa_b1  = (const float*)d_in[2];
    const float* pa_w2  = (const float*)d_in[3];
    const float* pa_b2  = (const float*)d_in[4];
    const float* pa_w3  = (const float*)d_in[5];
    const float* pa_b3  = (const float*)d_in[6];
    const float* pa_cw1 = (const float*)d_in[7];
    const float* pa_cb1 = (const float*)d_in[8];
    const float* pa_cw2 = (const float*)d_in[9];
    const float* pa_cb2 = (const float*)d_in[10];
    const float* kv_w   = (const float*)d_in[11];
    const float* kv_b   = (const float*)d_in[12];
    const float* out_w1 = (const float*)d_in[13];
    const float* out_b1 = (const float*)d_in[14];
    const float* out_w2 = (const float*)d_in[15];
    const float* out_b2 = (const float*)d_in[16];
    const float* scales = (const float*)d_in[17];
    float* out = (float*)d_out;
    float* ws  = (float*)d_ws;

    float* weff = ws + OFF_WEFF;
    float* beff = ws + OFF_BEFF;
    float* hid  = ws + OFF_HID;
    float* qkv  = ws + OFF_QKV;
    float* kbuf = ws + OFF_K;
    float* vbuf = ws + OFF_V;
    float* attn = ws + OFF_ATTN;

    k_fold<<<NRATES*OC, CIN*9, 0, stream>>>(pa_cw1, pa_cb1, pa_w1, pa_b1,
                                            pa_w2, pa_b2, pa_w3, pa_b3, weff, beff);
    k_hidden<<<BN*24*9, 256, 0, stream>>>(x, weff, beff, hid);
    k_qkv<<<BN*24*9, 256, 0, stream>>>(hid, pa_cw2, pa_cb2, qkv);
    k_tokv<<<BN*2*PK*8/256, 256, 0, stream>>>(qkv, kv_w, kv_b, kbuf, vbuf);
    hipMemsetAsync(attn, 0, (size_t)SZ_ATTN*sizeof(float), stream);
    k_attn<<<BB*NVIEW*NVIEW*2*9, 256, 0, stream>>>(qkv, kbuf, vbuf, attn);
    k_out<<<BN*9, 256, 0, stream>>>(attn, qkv, scales, out_w1, out_b1,
                                    out_w2, out_b2, out);
}

// Round 2
// 840.548 us; speedup vs baseline: 9.0324x; 9.0324x over previous
//
#include <hip/hip_runtime.h>
#include <math.h>

#define BB 2
#define NVIEW 6
#define BN 12
#define CIN 64
#define HH 48
#define WW 48
#define PP (HH*WW)        // 2304
#define OC 192
#define HPA 192
#define HIDP 64
#define KHW 16
#define PK 256
#define PADW 54
#define PADA (PADW*PADW)  // 2916

// ---- workspace layout (float elements) ----
#define OFF_WEFF 0
#define SZ_WEFF (3*OC*CIN*9)               // 331776, layout [r][ocg24][ic64][tap9][j8]
#define OFF_BEFF (OFF_WEFF + SZ_WEFF)
#define SZ_BEFF 256
#define OFF_WKV (OFF_BEFF + SZ_BEFF)
#define SZ_WKV (9*64*64)                   // 36864, layout [tap][ic][oc]
#define OFF_PAD (OFF_WKV + SZ_WKV)
#define SZ_PAD (BN*CIN*PADA)               // 2239488
#define OFF_HID (OFF_PAD + SZ_PAD)
#define SZ_HID (BN*OC*PP)                  // 5308416 (aliased by convtmp, then attn0/attn1)
#define OFF_QKV (OFF_HID + SZ_HID)
#define SZ_QKV (BN*OC*PP)
#define OFF_K (OFF_QKV + SZ_QKV)
#define SZ_K (BN*PK*HIDP)                  // [bn][k][d]
#define OFF_V (OFF_K + SZ_K)
#define SZ_V (BN*PK*HIDP)
#define SZ_ATTNP (BN*PP*HIDP)              // 1769472 per partial

// K1: fold pa_cw1 (192x576) into 3 effective dilated convs, layout [r][ocg][ic][tap][8]
__global__ void k_fold(const float* __restrict__ cw1, const float* __restrict__ cb1,
                       const float* __restrict__ w1, const float* __restrict__ b1,
                       const float* __restrict__ w2, const float* __restrict__ b2,
                       const float* __restrict__ w3, const float* __restrict__ b3,
                       float* __restrict__ weff, float* __restrict__ beff) {
    int r = blockIdx.x / OC;
    int o = blockIdx.x % OC;
    int t = threadIdx.x;                   // ic*9 + tap
    int ic = t / 9, tap = t % 9;
    const float* w = (r==0) ? w1 : (r==1) ? w2 : w3;
    float acc = 0.f;
    for (int c = 0; c < HPA; ++c)
        acc += cw1[o*(HPA*3) + r*HPA + c] * w[c*(CIN*9) + t];
    weff[(((size_t)(r*24 + o/8)*64 + ic)*9 + tap)*8 + (o%8)] = acc;
    if (r == 0 && t == 0) {
        float bacc = cb1[o];
        for (int rr = 0; rr < 3; ++rr) {
            const float* bb = (rr==0)?b1:(rr==1)?b2:b3;
            for (int c = 0; c < HPA; ++c)
                bacc += cw1[o*(HPA*3) + rr*HPA + c] * bb[c];
        }
        beff[o] = bacc;
    }
}

// K1b: transpose kv_w [oc][ic][tap] -> [tap][ic][oc]
__global__ void k_wkv(const float* __restrict__ kvw, float* __restrict__ wkv2) {
    int idx = blockIdx.x*256 + threadIdx.x;
    if (idx >= 9*64*64) return;
    int tap = idx / 4096, rest = idx % 4096;
    int ic = rest / 64, oc = rest % 64;
    wkv2[idx] = kvw[(oc*64 + ic)*9 + tap];
}

// K1c: padded x [bn][ic][54][54], 3-halo zeros
__global__ void k_pad(const float* __restrict__ x, float* __restrict__ pad) {
    int idx = blockIdx.x*256 + threadIdx.x;
    if (idx >= SZ_PAD) return;
    int px = idx % PADW, py = (idx/PADW) % PADW, c2 = idx/PADA;
    float v = 0.f;
    if (py >= 3 && py < 51 && px >= 3 && px < 51)
        v = x[(size_t)c2*PP + (py-3)*WW + (px-3)];
    pad[idx] = v;
}

// K2: hidden = relu( sum_r dilconv(pad, Weff_r) + beff )
__global__ __launch_bounds__(256) void k_hidden(const float* __restrict__ pad,
        const float* __restrict__ weff, const float* __restrict__ beff,
        float* __restrict__ hid) {
    int bx = blockIdx.x;
    int pb = bx % 9; bx /= 9;
    int ocg = bx % 24; bx /= 24;
    int bn = bx;
    int p = pb*256 + threadIdx.x;
    int y = p / WW, x0 = p % WW;
    int base = (y+3)*PADW + (x0+3);
    float acc[8] = {0,0,0,0,0,0,0,0};
    const float* xr = pad + (size_t)bn*CIN*PADA;
    #pragma unroll
    for (int r = 0; r < 3; ++r) {
        int d = r+1;
        const float* wr = weff + ((size_t)(r*24 + ocg)*64)*72;
        for (int ic = 0; ic < CIN; ++ic) {
            const float* xp = xr + ic*PADA + base;
            const float* wp = wr + ic*72;
            float xv[9];
            #pragma unroll
            for (int ky = 0; ky < 3; ++ky)
                #pragma unroll
                for (int kx = 0; kx < 3; ++kx)
                    xv[ky*3+kx] = xp[d*((ky-1)*PADW + (kx-1))];
            #pragma unroll
            for (int t = 0; t < 9; ++t)
                #pragma unroll
                for (int j = 0; j < 8; ++j)
                    acc[j] += wp[t*8+j] * xv[t];
        }
    }
    float* hb = hid + (size_t)bn*OC*PP;
    int oc0 = ocg*8;
    #pragma unroll
    for (int j = 0; j < 8; ++j)
        hb[(oc0+j)*PP + p] = fmaxf(acc[j] + beff[oc0+j], 0.f);
}

// K3: qkv = relu( cw2 @ hidden + cb2 )
__global__ __launch_bounds__(256) void k_qkv(const float* __restrict__ hid,
        const float* __restrict__ cw2, const float* __restrict__ cb2,
        float* __restrict__ qkv) {
    int bx = blockIdx.x;
    int pb = bx % 9; bx /= 9;
    int ocg = bx % 24; bx /= 24;
    int bn = bx;
    int p = pb*256 + threadIdx.x;
    int oc0 = ocg*8;
    float acc[8] = {0,0,0,0,0,0,0,0};
    const float* hb = hid + (size_t)bn*OC*PP;
    for (int c = 0; c < OC; ++c) {
        float hv = hb[c*PP + p];
        #pragma unroll
        for (int j = 0; j < 8; ++j)
            acc[j] += cw2[(oc0+j)*OC + c] * hv;
    }
    float* qb = qkv + (size_t)bn*OC*PP;
    #pragma unroll
    for (int j = 0; j < 8; ++j)
        qb[(oc0+j)*PP + p] = fmaxf(acc[j] + cb2[oc0+j], 0.f);
}

// K4a: full-res conv3x3 + bias + relu on xk/xv -> convtmp [bn][kv][dg][p][8]
__global__ __launch_bounds__(256) void k_kvconv(const float* __restrict__ qkv,
        const float* __restrict__ wkv2, const float* __restrict__ kvb,
        float* __restrict__ convtmp) {
    int bx = blockIdx.x;
    int pb = bx % 9; bx /= 9;
    int dg = bx % 8; bx /= 8;
    int kv = bx % 2; bx /= 2;
    int bn = bx;
    int p = pb*256 + threadIdx.x;
    int y = p / WW, x0 = p % WW;
    int d0 = dg*8;
    const float* src = qkv + ((size_t)bn*OC + (1+kv)*HIDP)*PP;
    float acc[8] = {0,0,0,0,0,0,0,0};
    #pragma unroll
    for (int ky = 0; ky < 3; ++ky) {
        int yy = y + ky - 1;
        bool rowok = (yy >= 0 && yy < HH);
        #pragma unroll
        for (int kx = 0; kx < 3; ++kx) {
            int xx = x0 + kx - 1;
            if (!rowok || xx < 0 || xx >= WW) continue;
            int off = (ky-1)*WW + (kx-1);
            const float* wt = wkv2 + (ky*3+kx)*4096 + d0;
            for (int ic = 0; ic < HIDP; ++ic) {
                float xval = src[ic*PP + p + off];
                #pragma unroll
                for (int j = 0; j < 8; ++j)
                    acc[j] += wt[ic*64 + j] * xval;
            }
        }
    }
    float* dst = convtmp + (((size_t)(bn*2+kv)*8 + dg)*PP + p)*8;
    #pragma unroll
    for (int j = 0; j < 8; ++j)
        dst[j] = fmaxf(acc[j] + kvb[d0+j], 0.f);
}

// K4b: 3x3 avgpool -> kbuf/vbuf [bn][pp][d]
__global__ __launch_bounds__(256) void k_pool(const float* __restrict__ convtmp,
        float* __restrict__ kbuf, float* __restrict__ vbuf) {
    int idx = blockIdx.x*256 + threadIdx.x;
    int dg = idx % 8; idx /= 8;
    int pp = idx % PK; idx /= PK;
    int kv = idx % 2; idx /= 2;
    int bn = idx;
    int qy = pp / KHW, qx = pp % KHW;
    float s[8] = {0,0,0,0,0,0,0,0};
    const float* base = convtmp + ((size_t)(bn*2+kv)*8 + dg)*PP*8;
    #pragma unroll
    for (int sy = 0; sy < 3; ++sy)
        #pragma unroll
        for (int sx = 0; sx < 3; ++sx) {
            const float* c = base + ((qy*3+sy)*WW + qx*3+sx)*8;
            #pragma unroll
            for (int j = 0; j < 8; ++j) s[j] += c[j];
        }
    float sc = (kv==0) ? (1.f/9.f) : (1.f/81.f);
    float* dst = ((kv==0) ? kbuf : vbuf) + ((size_t)bn*PK + pp)*HIDP + dg*8;
    #pragma unroll
    for (int j = 0; j < 8; ++j) dst[j] = s[j]*sc;
}

// K5: leave-one-out sigmoid attention, flash-style, LDS-staged K/V.
// block: (b, n, ptile of 64 queries, ks key-half). thread: (q_local, dg of 16 d).
__global__ __launch_bounds__(256) void k_attn2(const float* __restrict__ qkv,
        const float* __restrict__ kbuf, const float* __restrict__ vbuf,
        float* __restrict__ attnp) {
    int bid = blockIdx.x;
    int ks = bid & 1; bid >>= 1;
    int pt = bid % 36; bid /= 36;
    int n = bid % NVIEW; int b = bid / NVIEW;
    int tid = threadIdx.x;
    int q_local = tid >> 2, dg = tid & 3;
    int p = pt*64 + q_local;
    int bnq = b*NVIEW + n;

    __shared__ float Ks[2048];
    __shared__ float Vs[2048];

    const float* qb = qkv + (size_t)bnq*OC*PP;
    float q[16];
    #pragma unroll
    for (int i = 0; i < 16; ++i) q[i] = qb[(dg*16+i)*PP + p];
    float acc[16];
    #pragma unroll
    for (int i = 0; i < 16; ++i) acc[i] = 0.f;

    for (int mi = 0; mi < NVIEW-1; ++mi) {
        int m = mi + (mi >= n ? 1 : 0);
        int bnk = b*NVIEW + m;
        const float* kb = kbuf + ((size_t)bnk*PK + ks*128)*HIDP;
        const float* vb = vbuf + ((size_t)bnk*PK + ks*128)*HIDP;
        for (int kt = 0; kt < 4; ++kt) {
            __syncthreads();
            *(float4*)&Ks[tid*8]   = *(const float4*)&kb[kt*2048 + tid*8];
            *(float4*)&Ks[tid*8+4] = *(const float4*)&kb[kt*2048 + tid*8 + 4];
            *(float4*)&Vs[tid*8]   = *(const float4*)&vb[kt*2048 + tid*8];
            *(float4*)&Vs[tid*8+4] = *(const float4*)&vb[kt*2048 + tid*8 + 4];
            __syncthreads();
            #pragma unroll 2
            for (int kk = 0; kk < 32; ++kk) {
                const float* kp = &Ks[kk*64 + dg*16];
                float dot = 0.f;
                #pragma unroll
                for (int i = 0; i < 16; ++i) dot += q[i]*kp[i];
                dot += __shfl_xor(dot, 1);
                dot += __shfl_xor(dot, 2);
                float e = __expf(-dot*0.125f);
                float a = __builtin_amdgcn_rcpf(1.f + e);
                const float* vp = &Vs[kk*64 + dg*16];
                #pragma unroll
                for (int i = 0; i < 16; ++i) acc[i] += a*vp[i];
            }
        }
    }
    float* dst = attnp + (size_t)ks*SZ_ATTNP + ((size_t)bnq*PP + p)*HIDP + dg*16;
    #pragma unroll
    for (int i = 0; i < 4; ++i)
        *(float4*)&dst[i*4] = make_float4(acc[i*4], acc[i*4+1], acc[i*4+2], acc[i*4+3]);
}

// K6: out = relu(W2 relu(W1 relu(attn0+attn1 + scale*xv) + b1) + b2)
__global__ __launch_bounds__(256) void k_out(const float* __restrict__ attnp,
        const float* __restrict__ qkv, const float* __restrict__ scales,
        const float* __restrict__ w1, const float* __restrict__ b1,
        const float* __restrict__ w2, const float* __restrict__ b2,
        float* __restrict__ out) {
    int bx = blockIdx.x;
    int pb = bx % 9; int bn = bx / 9;
    int p = pb*256 + threadIdx.x;
    int n = bn % NVIEW;
    float sc = scales[n];
    const float* a0 = attnp + ((size_t)bn*PP + p)*HIDP;
    const float* a1 = a0 + SZ_ATTNP;
    const float* xvb = qkv + ((size_t)bn*OC + 2*HIDP)*PP;
    float res[64];
    #pragma unroll
    for (int i = 0; i < 64; ++i)
        res[i] = fmaxf(a0[i] + a1[i] + sc*xvb[i*PP+p], 0.f);
    float t[64];
    #pragma unroll
    for (int o = 0; o < 64; ++o) {
        float a = b1[o];
        #pragma unroll
        for (int i = 0; i < 64; ++i) a += w1[o*64+i]*res[i];
        t[o] = fmaxf(a, 0.f);
    }
    float* ob = out + (size_t)bn*HIDP*PP;
    #pragma unroll
    for (int o = 0; o < 64; ++o) {
        float a = b2[o];
        #pragma unroll
        for (int i = 0; i < 64; ++i) a += w2[o*64+i]*t[i];
        ob[o*PP+p] = fmaxf(a, 0.f);
    }
}

extern "C" void kernel_launch(void* const* d_in, const int* in_sizes, int n_in,
                              void* d_out, int out_size, void* d_ws, size_t ws_size,
                              hipStream_t stream) {
    (void)in_sizes; (void)n_in; (void)out_size; (void)ws_size;
    const float* x      = (const float*)d_in[0];
    const float* pa_w1  = (const float*)d_in[1];
    const float* pa_b1  = (const float*)d_in[2];
    const float* pa_w2  = (const float*)d_in[3];
    const float* pa_b2  = (const float*)d_in[4];
    const float* pa_w3  = (const float*)d_in[5];
    const float* pa_b3  = (const float*)d_in[6];
    const float* pa_cw1 = (const float*)d_in[7];
    const float* pa_cb1 = (const float*)d_in[8];
    const float* pa_cw2 = (const float*)d_in[9];
    const float* pa_cb2 = (const float*)d_in[10];
    const float* kv_w   = (const float*)d_in[11];
    const float* kv_b   = (const float*)d_in[12];
    const float* out_w1 = (const float*)d_in[13];
    const float* out_b1 = (const float*)d_in[14];
    const float* out_w2 = (const float*)d_in[15];
    const float* out_b2 = (const float*)d_in[16];
    const float* scales = (const float*)d_in[17];
    float* out = (float*)d_out;
    float* ws  = (float*)d_ws;

    float* weff = ws + OFF_WEFF;
    float* beff = ws + OFF_BEFF;
    float* wkv2 = ws + OFF_WKV;
    float* pad  = ws + OFF_PAD;
    float* hid  = ws + OFF_HID;      // aliased: convtmp, then attn partials
    float* qkv  = ws + OFF_QKV;
    float* kbuf = ws + OFF_K;
    float* vbuf = ws + OFF_V;
    float* convtmp = hid;
    float* attnp   = hid;

    k_fold<<<3*OC, CIN*9, 0, stream>>>(pa_cw1, pa_cb1, pa_w1, pa_b1,
                                       pa_w2, pa_b2, pa_w3, pa_b3, weff, beff);
    k_wkv<<<(SZ_WKV+255)/256, 256, 0, stream>>>(kv_w, wkv2);
    k_pad<<<(SZ_PAD+255)/256, 256, 0, stream>>>(x, pad);
    k_hidden<<<BN*24*9, 256, 0, stream>>>(pad, weff, beff, hid);
    k_qkv<<<BN*24*9, 256, 0, stream>>>(hid, pa_cw2, pa_cb2, qkv);
    k_kvconv<<<BN*2*8*9, 256, 0, stream>>>(qkv, wkv2, kv_b, convtmp);
    k_pool<<<BN*2*PK*8/256, 256, 0, stream>>>(convtmp, kbuf, vbuf);
    k_attn2<<<BB*NVIEW*36*2, 256, 0, stream>>>(qkv, kbuf, vbuf, attnp);
    k_out<<<BN*9, 256, 0, stream>>>(attnp, qkv, scales, out_w1, out_b1,
                                    out_w2, out_b2, out);
}

// Round 3
// 552.553 us; speedup vs baseline: 13.7402x; 1.5212x over previous
//
#include <hip/hip_runtime.h>
#include <hip/hip_bf16.h>
#include <math.h>

#define BB 2
#define NVIEW 6
#define BN 12
#define CIN 64
#define HH 48
#define WW 48
#define PP (HH*WW)        // 2304
#define OC 192
#define HPA 192
#define HIDP 64
#define KHW 16
#define PK 256
#define PADW 54
#define PADA (PADW*PADW)  // 2916
#define NTOT (BN*PP)      // 27648
#define K1 1728           // 27 taps * 64 ic, ordering k = r*576 + tap*64 + ic

typedef __attribute__((ext_vector_type(8))) short bf16x8;
typedef __attribute__((ext_vector_type(4))) float f32x4;

// ---- workspace layout (float elements) ----
#define OFF_WEFFB 0
#define SZ_WEFFB_FL (OC*K1/2)              // 165888 (bf16 x 331776)
#define OFF_BEFF (OFF_WEFFB + SZ_WEFFB_FL)
#define SZ_BEFF 256
#define OFF_CW2B (OFF_BEFF + SZ_BEFF)
#define SZ_CW2B_FL (OC*OC/2)               // 18432
#define OFF_WKV (OFF_CW2B + SZ_CW2B_FL)
#define SZ_WKV (9*64*64)                   // fp32, [tap][ic][oc]
#define OFF_PADXT (OFF_WKV + SZ_WKV)
#define SZ_PADXT_FL (BN*PADA*64/2)         // 1119744 (bf16 channels-last padded x)
#define OFF_SHARED (OFF_PADXT + SZ_PADXT_FL)
#define SZ_SHARED (BN*2*8*PP*8)            // 3538944 fl: hid_bt(bf16) / convtmp / attnp
#define OFF_QKV (OFF_SHARED + SZ_SHARED)
#define SZ_QKV (BN*OC*PP)                  // 5308416 fp32
#define OFF_K (OFF_QKV + SZ_QKV)
#define SZ_K (BN*PK*HIDP)
#define OFF_V (OFF_K + SZ_K)
#define SZ_V (BN*PK*HIDP)
#define SZ_ATTNP (BN*PP*HIDP)              // 1769472 per partial

__device__ __forceinline__ void load_lds16(const void* g, void* l) {
    __builtin_amdgcn_global_load_lds(
        (const __attribute__((address_space(1))) unsigned int*)g,
        (__attribute__((address_space(3))) unsigned int*)l, 16, 0, 0);
}

// K1: fold pa_cw1 (192x576) into 3 effective dilated convs -> bf16 [oc][r*576+tap*64+ic]
__global__ void k_fold(const float* __restrict__ cw1, const float* __restrict__ cb1,
                       const float* __restrict__ w1, const float* __restrict__ b1,
                       const float* __restrict__ w2, const float* __restrict__ b2,
                       const float* __restrict__ w3, const float* __restrict__ b3,
                       __hip_bfloat16* __restrict__ weffb, float* __restrict__ beff) {
    int r = blockIdx.x / OC;
    int o = blockIdx.x % OC;
    int t = threadIdx.x;                   // ic*9 + tap
    int ic = t / 9, tap = t % 9;
    const float* w = (r==0) ? w1 : (r==1) ? w2 : w3;
    float acc = 0.f;
    for (int c = 0; c < HPA; ++c)
        acc += cw1[o*(HPA*3) + r*HPA + c] * w[c*(CIN*9) + t];
    weffb[(size_t)o*K1 + r*576 + tap*64 + ic] = __float2bfloat16(acc);
    if (r == 0 && t == 0) {
        float bacc = cb1[o];
        for (int rr = 0; rr < 3; ++rr) {
            const float* bb = (rr==0)?b1:(rr==1)?b2:b3;
            for (int c = 0; c < HPA; ++c)
                bacc += cw1[o*(HPA*3) + rr*HPA + c] * bb[c];
        }
        beff[o] = bacc;
    }
}

// K1b: transpose kv_w [oc][ic][tap] -> [tap][ic][oc] fp32
__global__ void k_wkv(const float* __restrict__ kvw, float* __restrict__ wkv2) {
    int idx = blockIdx.x*256 + threadIdx.x;
    if (idx >= 9*64*64) return;
    int tap = idx / 4096, rest = idx % 4096;
    int ic = rest / 64, oc = rest % 64;
    wkv2[idx] = kvw[(oc*64 + ic)*9 + tap];
}

// K1c: cw2 -> bf16 [oc][ic]
__global__ void k_wcvt(const float* __restrict__ cw2, __hip_bfloat16* __restrict__ cw2b) {
    int idx = blockIdx.x*256 + threadIdx.x;
    if (idx < OC*OC) cw2b[idx] = __float2bfloat16(cw2[idx]);
}

// K1d: channels-last padded x, bf16: padxT[bn][spos(54x54)][ic(64)]
__global__ void k_padxT(const float* __restrict__ x, __hip_bfloat16* __restrict__ padxT) {
    int idx = blockIdx.x*256 + threadIdx.x;
    if (idx >= BN*PADA) return;
    int spos = idx % PADA; int bn = idx / PADA;
    int sy = spos / PADW, sx = spos % PADW;
    __hip_bfloat16* dst = padxT + (size_t)idx*64;
    if (sy >= 3 && sy < 51 && sx >= 3 && sx < 51) {
        const float* src = x + (size_t)bn*CIN*PP + (sy-3)*WW + (sx-3);
        #pragma unroll 8
        for (int ic = 0; ic < 64; ++ic) dst[ic] = __float2bfloat16(src[ic*PP]);
    } else {
        #pragma unroll 8
        for (int ic = 0; ic < 64; ++ic) dst[ic] = __float2bfloat16(0.f);
    }
}

// GEMM1 (implicit dilated conv): hid_bt[n][oc] = relu( weffb[oc][k] * B[k][n] + beff )
// B[k=(r,tap,ic)][n] gathered from padxT via wave-uniform tap offset.
// tile 64(M) x 128(N) x 64(K), 4 waves, each wave 32x64 (2x4 frags 16x16x32).
__global__ __launch_bounds__(256) void k_gemm1(const __hip_bfloat16* __restrict__ wA,
        const __hip_bfloat16* __restrict__ pxT, const float* __restrict__ beff,
        __hip_bfloat16* __restrict__ hidbt) {
    __shared__ char smem[24576];           // A: [64][64]bf16 @0 (8KB), B: [128][64] @8192 (16KB)
    int tid = threadIdx.x;
    int wid = tid >> 6, lane = tid & 63;
    int tileN = blockIdx.x * 128, tileM = blockIdx.y * 64;

    // per-thread staging bases: 6 segments of 1KB each
    size_t gbase[6];
    #pragma unroll
    for (int s2 = 0; s2 < 6; ++s2) {
        int seg = wid*6 + s2;
        if (seg < 8) {
            int row = seg*8 + (lane>>3);
            gbase[s2] = (size_t)(tileM + row)*K1 + (lane&7)*8;
        } else {
            int n = tileN + (seg-8)*8 + (lane>>3);
            int bn = n / PP, p = n % PP;
            int py = p / WW, px = p % WW;
            gbase[s2] = ((size_t)bn*PADA + (py+3)*PADW + (px+3))*64 + (lane&7)*8;
        }
    }
    int wr = wid >> 1, wc = wid & 1;
    int aoff[2], boff[4];
    #pragma unroll
    for (int m = 0; m < 2; ++m)
        aoff[m] = ((wr*32 + m*16 + (lane&15))*64 + (lane>>4)*8)*2;
    #pragma unroll
    for (int nf = 0; nf < 4; ++nf)
        boff[nf] = 8192 + ((wc*64 + nf*16 + (lane&15))*64 + (lane>>4)*8)*2;

    f32x4 acc[2][4];
    #pragma unroll
    for (int m = 0; m < 2; ++m)
        #pragma unroll
        for (int nf = 0; nf < 4; ++nf) acc[m][nf] = (f32x4){0.f,0.f,0.f,0.f};

    for (int kt = 0; kt < 27; ++kt) {
        int r_ = kt / 9, tap = kt - r_*9;
        int dy = tap/3 - 1, dx = tap%3 - 1;
        int doff = (r_+1)*(dy*PADW + dx);   // wave-uniform spatial shift
        __syncthreads();
        #pragma unroll
        for (int s2 = 0; s2 < 6; ++s2) {
            int seg = wid*6 + s2;
            const __hip_bfloat16* g = (seg < 8) ? wA + gbase[s2] + kt*64
                                                : pxT + gbase[s2] + (size_t)doff*64;
            load_lds16(g, smem + seg*1024);
        }
        __syncthreads();
        bf16x8 a[2][2], b[4][2];
        #pragma unroll
        for (int m = 0; m < 2; ++m)
            #pragma unroll
            for (int kk = 0; kk < 2; ++kk)
                a[m][kk] = *(const bf16x8*)(smem + aoff[m] + kk*64);
        #pragma unroll
        for (int nf = 0; nf < 4; ++nf)
            #pragma unroll
            for (int kk = 0; kk < 2; ++kk)
                b[nf][kk] = *(const bf16x8*)(smem + boff[nf] + kk*64);
        #pragma unroll
        for (int kk = 0; kk < 2; ++kk)
            #pragma unroll
            for (int m = 0; m < 2; ++m)
                #pragma unroll
                for (int nf = 0; nf < 4; ++nf)
                    acc[m][nf] = __builtin_amdgcn_mfma_f32_16x16x32_bf16(
                        a[m][kk], b[nf][kk], acc[m][nf], 0, 0, 0);
    }
    #pragma unroll
    for (int m = 0; m < 2; ++m) {
        int rbase = tileM + wr*32 + m*16 + (lane>>4)*4;
        float4 bz = *(const float4*)&beff[rbase];
        #pragma unroll
        for (int nf = 0; nf < 4; ++nf) {
            int col = tileN + wc*64 + nf*16 + (lane&15);
            union { ushort4 u; __hip_bfloat16 h[4]; } cv;
            cv.h[0] = __float2bfloat16(fmaxf(acc[m][nf][0] + bz.x, 0.f));
            cv.h[1] = __float2bfloat16(fmaxf(acc[m][nf][1] + bz.y, 0.f));
            cv.h[2] = __float2bfloat16(fmaxf(acc[m][nf][2] + bz.z, 0.f));
            cv.h[3] = __float2bfloat16(fmaxf(acc[m][nf][3] + bz.w, 0.f));
            *(ushort4*)&hidbt[(size_t)col*OC + rbase] = cv.u;
        }
    }
}

// GEMM2: qkv[bn][oc][p] = relu( cw2b[oc][k=192] * hid_bt[n][k] + cb2 )  fp32 out
__global__ __launch_bounds__(256) void k_gemm2(const __hip_bfloat16* __restrict__ wA,
        const __hip_bfloat16* __restrict__ Bt, const float* __restrict__ cb2,
        float* __restrict__ qkv) {
    __shared__ char smem[24576];
    int tid = threadIdx.x;
    int wid = tid >> 6, lane = tid & 63;
    int tileN = blockIdx.x * 128, tileM = blockIdx.y * 64;
    size_t gbase[6]; const __hip_bfloat16* gsrc[6];
    #pragma unroll
    for (int s2 = 0; s2 < 6; ++s2) {
        int seg = wid*6 + s2;
        if (seg < 8) {
            int row = seg*8 + (lane>>3);
            gbase[s2] = (size_t)(tileM + row)*OC + (lane&7)*8;
            gsrc[s2] = wA;
        } else {
            int n = tileN + (seg-8)*8 + (lane>>3);
            gbase[s2] = (size_t)n*OC + (lane&7)*8;
            gsrc[s2] = Bt;
        }
    }
    int wr = wid >> 1, wc = wid & 1;
    int aoff[2], boff[4];
    #pragma unroll
    for (int m = 0; m < 2; ++m)
        aoff[m] = ((wr*32 + m*16 + (lane&15))*64 + (lane>>4)*8)*2;
    #pragma unroll
    for (int nf = 0; nf < 4; ++nf)
        boff[nf] = 8192 + ((wc*64 + nf*16 + (lane&15))*64 + (lane>>4)*8)*2;
    f32x4 acc[2][4];
    #pragma unroll
    for (int m = 0; m < 2; ++m)
        #pragma unroll
        for (int nf = 0; nf < 4; ++nf) acc[m][nf] = (f32x4){0.f,0.f,0.f,0.f};

    for (int kt = 0; kt < 3; ++kt) {
        __syncthreads();
        #pragma unroll
        for (int s2 = 0; s2 < 6; ++s2)
            load_lds16(gsrc[s2] + gbase[s2] + kt*64, smem + (wid*6+s2)*1024);
        __syncthreads();
        bf16x8 a[2][2], b[4][2];
        #pragma unroll
        for (int m = 0; m < 2; ++m)
            #pragma unroll
            for (int kk = 0; kk < 2; ++kk)
                a[m][kk] = *(const bf16x8*)(smem + aoff[m] + kk*64);
        #pragma unroll
        for (int nf = 0; nf < 4; ++nf)
            #pragma unroll
            for (int kk = 0; kk < 2; ++kk)
                b[nf][kk] = *(const bf16x8*)(smem + boff[nf] + kk*64);
        #pragma unroll
        for (int kk = 0; kk < 2; ++kk)
            #pragma unroll
            for (int m = 0; m < 2; ++m)
                #pragma unroll
                for (int nf = 0; nf < 4; ++nf)
                    acc[m][nf] = __builtin_amdgcn_mfma_f32_16x16x32_bf16(
                        a[m][kk], b[nf][kk], acc[m][nf], 0, 0, 0);
    }
    #pragma unroll
    for (int m = 0; m < 2; ++m) {
        int rbase = tileM + wr*32 + m*16 + (lane>>4)*4;
        float4 cz = *(const float4*)&cb2[rbase];
        #pragma unroll
        for (int nf = 0; nf < 4; ++nf) {
            int col = tileN + wc*64 + nf*16 + (lane&15);
            int bn = col / PP, p = col % PP;
            float* dst = qkv + (size_t)bn*OC*PP + (size_t)rbase*PP + p;
            dst[0*PP] = fmaxf(acc[m][nf][0] + cz.x, 0.f);
            dst[1*PP] = fmaxf(acc[m][nf][1] + cz.y, 0.f);
            dst[2*PP] = fmaxf(acc[m][nf][2] + cz.z, 0.f);
            dst[3*PP] = fmaxf(acc[m][nf][3] + cz.w, 0.f);
        }
    }
}

// K4a: full-res conv3x3 + bias + relu on xk/xv -> convtmp [bn][kv][dg][p][8]
__global__ __launch_bounds__(256) void k_kvconv(const float* __restrict__ qkv,
        const float* __restrict__ wkv2, const float* __restrict__ kvb,
        float* __restrict__ convtmp) {
    int bx = blockIdx.x;
    int pb = bx % 9; bx /= 9;
    int dg = bx % 8; bx /= 8;
    int kv = bx % 2; bx /= 2;
    int bn = bx;
    int p = pb*256 + threadIdx.x;
    int y = p / WW, x0 = p % WW;
    int d0 = dg*8;
    const float* src = qkv + ((size_t)bn*OC + (1+kv)*HIDP)*PP;
    float acc[8] = {0,0,0,0,0,0,0,0};
    #pragma unroll
    for (int ky = 0; ky < 3; ++ky) {
        int yy = y + ky - 1;
        bool rowok = (yy >= 0 && yy < HH);
        #pragma unroll
        for (int kx = 0; kx < 3; ++kx) {
            int xx = x0 + kx - 1;
            if (!rowok || xx < 0 || xx >= WW) continue;
            int off = (ky-1)*WW + (kx-1);
            const float* wt = wkv2 + (ky*3+kx)*4096 + d0;
            for (int ic = 0; ic < HIDP; ++ic) {
                float xval = src[ic*PP + p + off];
                #pragma unroll
                for (int j = 0; j < 8; ++j)
                    acc[j] += wt[ic*64 + j] * xval;
            }
        }
    }
    float* dst = convtmp + (((size_t)(bn*2+kv)*8 + dg)*PP + p)*8;
    #pragma unroll
    for (int j = 0; j < 8; ++j)
        dst[j] = fmaxf(acc[j] + kvb[d0+j], 0.f);
}

// K4b: 3x3 avgpool -> kbuf/vbuf [bn][pp][d]
__global__ __launch_bounds__(256) void k_pool(const float* __restrict__ convtmp,
        float* __restrict__ kbuf, float* __restrict__ vbuf) {
    int idx = blockIdx.x*256 + threadIdx.x;
    int dg = idx % 8; idx /= 8;
    int pp = idx % PK; idx /= PK;
    int kv = idx % 2; idx /= 2;
    int bn = idx;
    int qy = pp / KHW, qx = pp % KHW;
    float s[8] = {0,0,0,0,0,0,0,0};
    const float* base = convtmp + ((size_t)(bn*2+kv)*8 + dg)*PP*8;
    #pragma unroll
    for (int sy = 0; sy < 3; ++sy)
        #pragma unroll
        for (int sx = 0; sx < 3; ++sx) {
            const float* c = base + ((qy*3+sy)*WW + qx*3+sx)*8;
            #pragma unroll
            for (int j = 0; j < 8; ++j) s[j] += c[j];
        }
    float sc = (kv==0) ? (1.f/9.f) : (1.f/81.f);
    float* dst = ((kv==0) ? kbuf : vbuf) + ((size_t)bn*PK + pp)*HIDP + dg*8;
    #pragma unroll
    for (int j = 0; j < 8; ++j) dst[j] = s[j]*sc;
}

// K5: leave-one-out sigmoid attention, LDS-staged K/V.
__global__ __launch_bounds__(256) void k_attn2(const float* __restrict__ qkv,
        const float* __restrict__ kbuf, const float* __restrict__ vbuf,
        float* __restrict__ attnp) {
    int bid = blockIdx.x;
    int ks = bid & 1; bid >>= 1;
    int pt = bid % 36; bid /= 36;
    int n = bid % NVIEW; int b = bid / NVIEW;
    int tid = threadIdx.x;
    int q_local = tid >> 2, dg = tid & 3;
    int p = pt*64 + q_local;
    int bnq = b*NVIEW + n;

    __shared__ float Ks[2048];
    __shared__ float Vs[2048];

    const float* qb = qkv + (size_t)bnq*OC*PP;
    float q[16];
    #pragma unroll
    for (int i = 0; i < 16; ++i) q[i] = qb[(dg*16+i)*PP + p];
    float acc[16];
    #pragma unroll
    for (int i = 0; i < 16; ++i) acc[i] = 0.f;

    for (int mi = 0; mi < NVIEW-1; ++mi) {
        int m = mi + (mi >= n ? 1 : 0);
        int bnk = b*NVIEW + m;
        const float* kb = kbuf + ((size_t)bnk*PK + ks*128)*HIDP;
        const float* vb = vbuf + ((size_t)bnk*PK + ks*128)*HIDP;
        for (int kt = 0; kt < 4; ++kt) {
            __syncthreads();
            *(float4*)&Ks[tid*8]   = *(const float4*)&kb[kt*2048 + tid*8];
            *(float4*)&Ks[tid*8+4] = *(const float4*)&kb[kt*2048 + tid*8 + 4];
            *(float4*)&Vs[tid*8]   = *(const float4*)&vb[kt*2048 + tid*8];
            *(float4*)&Vs[tid*8+4] = *(const float4*)&vb[kt*2048 + tid*8 + 4];
            __syncthreads();
            #pragma unroll 2
            for (int kk = 0; kk < 32; ++kk) {
                const float* kp = &Ks[kk*64 + dg*16];
                float dot = 0.f;
                #pragma unroll
                for (int i = 0; i < 16; ++i) dot += q[i]*kp[i];
                dot += __shfl_xor(dot, 1);
                dot += __shfl_xor(dot, 2);
                float e = __expf(-dot*0.125f);
                float a = __builtin_amdgcn_rcpf(1.f + e);
                const float* vp = &Vs[kk*64 + dg*16];
                #pragma unroll
                for (int i = 0; i < 16; ++i) acc[i] += a*vp[i];
            }
        }
    }
    float* dst = attnp + (size_t)ks*SZ_ATTNP + ((size_t)bnq*PP + p)*HIDP + dg*16;
    #pragma unroll
    for (int i = 0; i < 4; ++i)
        *(float4*)&dst[i*4] = make_float4(acc[i*4], acc[i*4+1], acc[i*4+2], acc[i*4+3]);
}

// K6: out = relu(W2 relu(W1 relu(attn0+attn1 + scale*xv) + b1) + b2)
__global__ __launch_bounds__(256) void k_out(const float* __restrict__ attnp,
        const float* __restrict__ qkv, const float* __restrict__ scales,
        const float* __restrict__ w1, const float* __restrict__ b1,
        const float* __restrict__ w2, const float* __restrict__ b2,
        float* __restrict__ out) {
    int bx = blockIdx.x;
    int pb = bx % 9; int bn = bx / 9;
    int p = pb*256 + threadIdx.x;
    int n = bn % NVIEW;
    float sc = scales[n];
    const float* a0 = attnp + ((size_t)bn*PP + p)*HIDP;
    const float* a1 = a0 + SZ_ATTNP;
    const float* xvb = qkv + ((size_t)bn*OC + 2*HIDP)*PP;
    float res[64];
    #pragma unroll
    for (int i = 0; i < 64; ++i)
        res[i] = fmaxf(a0[i] + a1[i] + sc*xvb[i*PP+p], 0.f);
    float t[64];
    #pragma unroll
    for (int o = 0; o < 64; ++o) {
        float a = b1[o];
        #pragma unroll
        for (int i = 0; i < 64; ++i) a += w1[o*64+i]*res[i];
        t[o] = fmaxf(a, 0.f);
    }
    float* ob = out + (size_t)bn*HIDP*PP;
    #pragma unroll
    for (int o = 0; o < 64; ++o) {
        float a = b2[o];
        #pragma unroll
        for (int i = 0; i < 64; ++i) a += w2[o*64+i]*t[i];
        ob[o*PP+p] = fmaxf(a, 0.f);
    }
}

extern "C" void kernel_launch(void* const* d_in, const int* in_sizes, int n_in,
                              void* d_out, int out_size, void* d_ws, size_t ws_size,
                              hipStream_t stream) {
    (void)in_sizes; (void)n_in; (void)out_size; (void)ws_size;
    const float* x      = (const float*)d_in[0];
    const float* pa_w1  = (const float*)d_in[1];
    const float* pa_b1  = (const float*)d_in[2];
    const float* pa_w2  = (const float*)d_in[3];
    const float* pa_b2  = (const float*)d_in[4];
    const float* pa_w3  = (const float*)d_in[5];
    const float* pa_b3  = (const float*)d_in[6];
    const float* pa_cw1 = (const float*)d_in[7];
    const float* pa_cb1 = (const float*)d_in[8];
    const float* pa_cw2 = (const float*)d_in[9];
    const float* pa_cb2 = (const float*)d_in[10];
    const float* kv_w   = (const float*)d_in[11];
    const float* kv_b   = (const float*)d_in[12];
    const float* out_w1 = (const float*)d_in[13];
    const float* out_b1 = (const float*)d_in[14];
    const float* out_w2 = (const float*)d_in[15];
    const float* out_b2 = (const float*)d_in[16];
    const float* scales = (const float*)d_in[17];
    float* out = (float*)d_out;
    float* ws  = (float*)d_ws;

    __hip_bfloat16* weffb = (__hip_bfloat16*)(ws + OFF_WEFFB);
    float* beff = ws + OFF_BEFF;
    __hip_bfloat16* cw2b = (__hip_bfloat16*)(ws + OFF_CW2B);
    float* wkv2 = ws + OFF_WKV;
    __hip_bfloat16* padxT = (__hip_bfloat16*)(ws + OFF_PADXT);
    __hip_bfloat16* hidbt = (__hip_bfloat16*)(ws + OFF_SHARED);
    float* convtmp = ws + OFF_SHARED;
    float* attnp   = ws + OFF_SHARED;
    float* qkv  = ws + OFF_QKV;
    float* kbuf = ws + OFF_K;
    float* vbuf = ws + OFF_V;

    k_fold<<<3*OC, CIN*9, 0, stream>>>(pa_cw1, pa_cb1, pa_w1, pa_b1,
                                       pa_w2, pa_b2, pa_w3, pa_b3, weffb, beff);
    k_wkv<<<(SZ_WKV+255)/256, 256, 0, stream>>>(kv_w, wkv2);
    k_wcvt<<<(OC*OC+255)/256, 256, 0, stream>>>(pa_cw2, cw2b);
    k_padxT<<<(BN*PADA+255)/256, 256, 0, stream>>>(x, padxT);
    k_gemm1<<<dim3(NTOT/128, 3), 256, 0, stream>>>(weffb, padxT, beff, hidbt);
    k_gemm2<<<dim3(NTOT/128, 3), 256, 0, stream>>>(cw2b, hidbt, pa_cb2, qkv);
    k_kvconv<<<BN*2*8*9, 256, 0, stream>>>(qkv, wkv2, kv_b, convtmp);
    k_pool<<<BN*2*PK*8/256, 256, 0, stream>>>(convtmp, kbuf, vbuf);
    k_attn2<<<BB*NVIEW*36*2, 256, 0, stream>>>(qkv, kbuf, vbuf, attnp);
    k_out<<<BN*9, 256, 0, stream>>>(attnp, qkv, scales, out_w1, out_b1,
                                    out_w2, out_b2, out);
}

// Round 4
// 334.557 us; speedup vs baseline: 22.6932x; 1.6516x over previous
//
#include <hip/hip_runtime.h>
#include <hip/hip_bf16.h>
#include <math.h>

#define BB 2
#define NVIEW 6
#define BN 12
#define CIN 64
#define HH 48
#define WW 48
#define PP (HH*WW)        // 2304
#define OC 192
#define HPA 192
#define HIDP 64
#define KHW 16
#define PK 256
#define PADW 54
#define PADA (PADW*PADW)  // 2916
#define NTOT (BN*PP)      // 27648
#define K1 1728           // 27 taps * 64 ic, ordering k = r*576 + tap*64 + ic

typedef __attribute__((ext_vector_type(8))) short bf16x8;
typedef __attribute__((ext_vector_type(4))) float f32x4;

// ---- workspace layout (float elements) ----
#define OFF_WEFFB 0
#define SZ_WEFFB_FL (OC*K1/2)              // 165888
#define OFF_BEFF (OFF_WEFFB + SZ_WEFFB_FL)
#define SZ_BEFF 256
#define OFF_CW2B (OFF_BEFF + SZ_BEFF)
#define SZ_CW2B_FL (OC*OC/2)               // 18432
#define OFF_WKV (OFF_CW2B + SZ_CW2B_FL)
#define SZ_WKV (9*64*64)                   // fp32 [tap][ic][oc]
#define OFF_PADXT (OFF_WKV + SZ_WKV)
#define SZ_PADXT_FL (BN*PADA*64/2)         // 1119744
#define OFF_QB16 (OFF_PADXT + SZ_PADXT_FL)
#define SZ_QB16_FL (BN*PP*64/2)            // 884736 (bf16 [bn][p][d])
#define OFF_KB16 (OFF_QB16 + SZ_QB16_FL)
#define SZ_KB16_FL (BN*PK*64/2)            // 98304 (bf16 [bn][k][d])
#define OFF_VB16T (OFF_KB16 + SZ_KB16_FL)
#define SZ_VB16T_FL (BN*64*PK/2)           // 98304 (bf16 [bn][d][k])
#define OFF_SHARED (OFF_VB16T + SZ_VB16T_FL)
#define SZ_SHARED (BN*2*8*PP*8)            // 3538944 fl: convtmp fp32 / attnp 2 partials
#define OFF_QKV (OFF_SHARED + SZ_SHARED)
#define SZ_QKV (BN*OC*PP)                  // fp32
#define SZ_ATTNP (BN*PP*HIDP)              // 1769472 per partial

__device__ __forceinline__ void load_lds16(const void* g, void* l) {
    __builtin_amdgcn_global_load_lds(
        (const __attribute__((address_space(1))) unsigned int*)g,
        (__attribute__((address_space(3))) unsigned int*)l, 16, 0, 0);
}

__device__ __forceinline__ unsigned short f2bu(float f) {
    __hip_bfloat16 h = __float2bfloat16(f);
    return *(unsigned short*)&h;
}

// K1: fold pa_cw1 (192x576) into 3 effective dilated convs -> bf16 [oc][r*576+tap*64+ic]
__global__ void k_fold(const float* __restrict__ cw1, const float* __restrict__ cb1,
                       const float* __restrict__ w1, const float* __restrict__ b1,
                       const float* __restrict__ w2, const float* __restrict__ b2,
                       const float* __restrict__ w3, const float* __restrict__ b3,
                       __hip_bfloat16* __restrict__ weffb, float* __restrict__ beff) {
    int r = blockIdx.x / OC;
    int o = blockIdx.x % OC;
    int t = threadIdx.x;                   // ic*9 + tap
    int ic = t / 9, tap = t % 9;
    const float* w = (r==0) ? w1 : (r==1) ? w2 : w3;
    float acc = 0.f;
    for (int c = 0; c < HPA; ++c)
        acc += cw1[o*(HPA*3) + r*HPA + c] * w[c*(CIN*9) + t];
    weffb[(size_t)o*K1 + r*576 + tap*64 + ic] = __float2bfloat16(acc);
    if (r == 0 && t == 0) {
        float bacc = cb1[o];
        for (int rr = 0; rr < 3; ++rr) {
            const float* bb = (rr==0)?b1:(rr==1)?b2:b3;
            for (int c = 0; c < HPA; ++c)
                bacc += cw1[o*(HPA*3) + rr*HPA + c] * bb[c];
        }
        beff[o] = bacc;
    }
}

// K1b: transpose kv_w [oc][ic][tap] -> [tap][ic][oc] fp32
__global__ void k_wkv(const float* __restrict__ kvw, float* __restrict__ wkv2) {
    int idx = blockIdx.x*256 + threadIdx.x;
    if (idx >= 9*64*64) return;
    int tap = idx / 4096, rest = idx % 4096;
    int ic = rest / 64, oc = rest % 64;
    wkv2[idx] = kvw[(oc*64 + ic)*9 + tap];
}

// K1c: cw2 -> bf16 [oc][ic]
__global__ void k_wcvt(const float* __restrict__ cw2, __hip_bfloat16* __restrict__ cw2b) {
    int idx = blockIdx.x*256 + threadIdx.x;
    if (idx < OC*OC) cw2b[idx] = __float2bfloat16(cw2[idx]);
}

// K1d: channels-last padded x, bf16: padxT[bn][spos(54x54)][ic(64)]
__global__ void k_padxT(const float* __restrict__ x, __hip_bfloat16* __restrict__ padxT) {
    int idx = blockIdx.x*256 + threadIdx.x;
    if (idx >= BN*PADA) return;
    int spos = idx % PADA; int bn = idx / PADA;
    int sy = spos / PADW, sx = spos % PADW;
    __hip_bfloat16* dst = padxT + (size_t)idx*64;
    if (sy >= 3 && sy < 51 && sx >= 3 && sx < 51) {
        const float* src = x + (size_t)bn*CIN*PP + (sy-3)*WW + (sx-3);
        #pragma unroll 8
        for (int ic = 0; ic < 64; ++ic) dst[ic] = __float2bfloat16(src[ic*PP]);
    } else {
        #pragma unroll 8
        for (int ic = 0; ic < 64; ++ic) dst[ic] = __float2bfloat16(0.f);
    }
}

// GEMM1 (implicit dilated conv): hid_bt[n][oc] = relu( weffb[oc][k] * B[k][n] + beff )
__global__ __launch_bounds__(256) void k_gemm1(const __hip_bfloat16* __restrict__ wA,
        const __hip_bfloat16* __restrict__ pxT, const float* __restrict__ beff,
        __hip_bfloat16* __restrict__ hidbt) {
    __shared__ __align__(16) char smem[24576];   // A [64][64] @0, B [128][64] @8192
    int tid = threadIdx.x;
    int wid = tid >> 6, lane = tid & 63;
    int tileN = blockIdx.x * 128, tileM = blockIdx.y * 64;

    size_t gbase[6];
    #pragma unroll
    for (int s2 = 0; s2 < 6; ++s2) {
        int seg = wid*6 + s2;
        if (seg < 8) {
            int row = seg*8 + (lane>>3);
            gbase[s2] = (size_t)(tileM + row)*K1 + (lane&7)*8;
        } else {
            int n = tileN + (seg-8)*8 + (lane>>3);
            int bn = n / PP, p = n % PP;
            int py = p / WW, px = p % WW;
            gbase[s2] = ((size_t)bn*PADA + (py+3)*PADW + (px+3))*64 + (lane&7)*8;
        }
    }
    int wr = wid >> 1, wc = wid & 1;
    int aoff[2], boff[4];
    #pragma unroll
    for (int m = 0; m < 2; ++m)
        aoff[m] = ((wr*32 + m*16 + (lane&15))*64 + (lane>>4)*8)*2;
    #pragma unroll
    for (int nf = 0; nf < 4; ++nf)
        boff[nf] = 8192 + ((wc*64 + nf*16 + (lane&15))*64 + (lane>>4)*8)*2;

    f32x4 acc[2][4];
    #pragma unroll
    for (int m = 0; m < 2; ++m)
        #pragma unroll
        for (int nf = 0; nf < 4; ++nf) acc[m][nf] = (f32x4){0.f,0.f,0.f,0.f};

    for (int kt = 0; kt < 27; ++kt) {
        int r_ = kt / 9, tap = kt - r_*9;
        int dy = tap/3 - 1, dx = tap%3 - 1;
        int doff = (r_+1)*(dy*PADW + dx);
        __syncthreads();
        #pragma unroll
        for (int s2 = 0; s2 < 6; ++s2) {
            int seg = wid*6 + s2;
            const __hip_bfloat16* g = (seg < 8) ? wA + gbase[s2] + kt*64
                                                : pxT + gbase[s2] + (size_t)doff*64;
            load_lds16(g, smem + seg*1024);
        }
        __syncthreads();
        bf16x8 a[2][2], b[4][2];
        #pragma unroll
        for (int m = 0; m < 2; ++m)
            #pragma unroll
            for (int kk = 0; kk < 2; ++kk)
                a[m][kk] = *(const bf16x8*)(smem + aoff[m] + kk*64);
        #pragma unroll
        for (int nf = 0; nf < 4; ++nf)
            #pragma unroll
            for (int kk = 0; kk < 2; ++kk)
                b[nf][kk] = *(const bf16x8*)(smem + boff[nf] + kk*64);
        #pragma unroll
        for (int kk = 0; kk < 2; ++kk)
            #pragma unroll
            for (int m = 0; m < 2; ++m)
                #pragma unroll
                for (int nf = 0; nf < 4; ++nf)
                    acc[m][nf] = __builtin_amdgcn_mfma_f32_16x16x32_bf16(
                        a[m][kk], b[nf][kk], acc[m][nf], 0, 0, 0);
    }
    #pragma unroll
    for (int m = 0; m < 2; ++m) {
        int rbase = tileM + wr*32 + m*16 + (lane>>4)*4;
        float4 bz = *(const float4*)&beff[rbase];
        #pragma unroll
        for (int nf = 0; nf < 4; ++nf) {
            int col = tileN + wc*64 + nf*16 + (lane&15);
            union { ushort4 u; __hip_bfloat16 h[4]; } cv;
            cv.h[0] = __float2bfloat16(fmaxf(acc[m][nf][0] + bz.x, 0.f));
            cv.h[1] = __float2bfloat16(fmaxf(acc[m][nf][1] + bz.y, 0.f));
            cv.h[2] = __float2bfloat16(fmaxf(acc[m][nf][2] + bz.z, 0.f));
            cv.h[3] = __float2bfloat16(fmaxf(acc[m][nf][3] + bz.w, 0.f));
            *(ushort4*)&hidbt[(size_t)col*OC + rbase] = cv.u;
        }
    }
}

// GEMM2: qkv[bn][oc][p] = relu( cw2b[oc][k=192] * hid_bt[n][k] + cb2 ), also qb16[bn][p][d<64]
__global__ __launch_bounds__(256) void k_gemm2(const __hip_bfloat16* __restrict__ wA,
        const __hip_bfloat16* __restrict__ Bt, const float* __restrict__ cb2,
        float* __restrict__ qkv, __hip_bfloat16* __restrict__ qb16) {
    __shared__ __align__(16) char smem[24576];
    int tid = threadIdx.x;
    int wid = tid >> 6, lane = tid & 63;
    int tileN = blockIdx.x * 128, tileM = blockIdx.y * 64;
    size_t gbase[6]; const __hip_bfloat16* gsrc[6];
    #pragma unroll
    for (int s2 = 0; s2 < 6; ++s2) {
        int seg = wid*6 + s2;
        if (seg < 8) {
            int row = seg*8 + (lane>>3);
            gbase[s2] = (size_t)(tileM + row)*OC + (lane&7)*8;
            gsrc[s2] = wA;
        } else {
            int n = tileN + (seg-8)*8 + (lane>>3);
            gbase[s2] = (size_t)n*OC + (lane&7)*8;
            gsrc[s2] = Bt;
        }
    }
    int wr = wid >> 1, wc = wid & 1;
    int aoff[2], boff[4];
    #pragma unroll
    for (int m = 0; m < 2; ++m)
        aoff[m] = ((wr*32 + m*16 + (lane&15))*64 + (lane>>4)*8)*2;
    #pragma unroll
    for (int nf = 0; nf < 4; ++nf)
        boff[nf] = 8192 + ((wc*64 + nf*16 + (lane&15))*64 + (lane>>4)*8)*2;
    f32x4 acc[2][4];
    #pragma unroll
    for (int m = 0; m < 2; ++m)
        #pragma unroll
        for (int nf = 0; nf < 4; ++nf) acc[m][nf] = (f32x4){0.f,0.f,0.f,0.f};

    for (int kt = 0; kt < 3; ++kt) {
        __syncthreads();
        #pragma unroll
        for (int s2 = 0; s2 < 6; ++s2)
            load_lds16(gsrc[s2] + gbase[s2] + kt*64, smem + (wid*6+s2)*1024);
        __syncthreads();
        bf16x8 a[2][2], b[4][2];
        #pragma unroll
        for (int m = 0; m < 2; ++m)
            #pragma unroll
            for (int kk = 0; kk < 2; ++kk)
                a[m][kk] = *(const bf16x8*)(smem + aoff[m] + kk*64);
        #pragma unroll
        for (int nf = 0; nf < 4; ++nf)
            #pragma unroll
            for (int kk = 0; kk < 2; ++kk)
                b[nf][kk] = *(const bf16x8*)(smem + boff[nf] + kk*64);
        #pragma unroll
        for (int kk = 0; kk < 2; ++kk)
            #pragma unroll
            for (int m = 0; m < 2; ++m)
                #pragma unroll
                for (int nf = 0; nf < 4; ++nf)
                    acc[m][nf] = __builtin_amdgcn_mfma_f32_16x16x32_bf16(
                        a[m][kk], b[nf][kk], acc[m][nf], 0, 0, 0);
    }
    #pragma unroll
    for (int m = 0; m < 2; ++m) {
        int rbase = tileM + wr*32 + m*16 + (lane>>4)*4;
        float4 cz = *(const float4*)&cb2[rbase];
        #pragma unroll
        for (int nf = 0; nf < 4; ++nf) {
            int col = tileN + wc*64 + nf*16 + (lane&15);
            int bn = col / PP, p = col % PP;
            float* dst = qkv + (size_t)bn*OC*PP + (size_t)rbase*PP + p;
            float v0 = fmaxf(acc[m][nf][0] + cz.x, 0.f);
            float v1 = fmaxf(acc[m][nf][1] + cz.y, 0.f);
            float v2 = fmaxf(acc[m][nf][2] + cz.z, 0.f);
            float v3 = fmaxf(acc[m][nf][3] + cz.w, 0.f);
            dst[0*PP] = v0; dst[1*PP] = v1; dst[2*PP] = v2; dst[3*PP] = v3;
            if (tileM == 0) {   // q channels: also write bf16 [n][d]
                ushort4 qv;
                qv.x = f2bu(v0); qv.y = f2bu(v1); qv.z = f2bu(v2); qv.w = f2bu(v3);
                *(ushort4*)&qb16[(size_t)col*64 + rbase] = qv;
            }
        }
    }
}

// K4a: full-res conv3x3 + bias + relu on xk/xv -> convtmp [bn][kv][dg][p][8]
__global__ __launch_bounds__(256) void k_kvconv(const float* __restrict__ qkv,
        const float* __restrict__ wkv2, const float* __restrict__ kvb,
        float* __restrict__ convtmp) {
    int bx = blockIdx.x;
    int pb = bx % 9; bx /= 9;
    int dg = bx % 8; bx /= 8;
    int kv = bx % 2; bx /= 2;
    int bn = bx;
    int p = pb*256 + threadIdx.x;
    int y = p / WW, x0 = p % WW;
    int d0 = dg*8;
    const float* src = qkv + ((size_t)bn*OC + (1+kv)*HIDP)*PP;
    float acc[8] = {0,0,0,0,0,0,0,0};
    #pragma unroll
    for (int ky = 0; ky < 3; ++ky) {
        int yy = y + ky - 1;
        bool rowok = (yy >= 0 && yy < HH);
        #pragma unroll
        for (int kx = 0; kx < 3; ++kx) {
            int xx = x0 + kx - 1;
            if (!rowok || xx < 0 || xx >= WW) continue;
            int off = (ky-1)*WW + (kx-1);
            const float* wt = wkv2 + (ky*3+kx)*4096 + d0;
            for (int ic = 0; ic < HIDP; ++ic) {
                float xval = src[ic*PP + p + off];
                #pragma unroll
                for (int j = 0; j < 8; ++j)
                    acc[j] += wt[ic*64 + j] * xval;
            }
        }
    }
    float* dst = convtmp + (((size_t)(bn*2+kv)*8 + dg)*PP + p)*8;
    #pragma unroll
    for (int j = 0; j < 8; ++j)
        dst[j] = fmaxf(acc[j] + kvb[d0+j], 0.f);
}

// K4b: 3x3 avgpool -> kbufb bf16 [bn][k][d], vbufT bf16 [bn][d][k]
__global__ __launch_bounds__(256) void k_pool(const float* __restrict__ convtmp,
        __hip_bfloat16* __restrict__ kbufb, __hip_bfloat16* __restrict__ vbufT) {
    int idx = blockIdx.x*256 + threadIdx.x;
    int dg = idx % 8; idx /= 8;
    int pp = idx % PK; idx /= PK;
    int kv = idx % 2; idx /= 2;
    int bn = idx;
    int qy = pp / KHW, qx = pp % KHW;
    float s[8] = {0,0,0,0,0,0,0,0};
    const float* base = convtmp + ((size_t)(bn*2+kv)*8 + dg)*PP*8;
    #pragma unroll
    for (int sy = 0; sy < 3; ++sy)
        #pragma unroll
        for (int sx = 0; sx < 3; ++sx) {
            const float* c = base + ((qy*3+sy)*WW + qx*3+sx)*8;
            #pragma unroll
            for (int j = 0; j < 8; ++j) s[j] += c[j];
        }
    if (kv == 0) {
        union { ushort4 u[2]; unsigned short h[8]; } cv;
        #pragma unroll
        for (int j = 0; j < 8; ++j) cv.h[j] = f2bu(s[j] * (1.f/9.f));
        ushort4* dst = (ushort4*)(kbufb + ((size_t)bn*PK + pp)*64 + dg*8);
        dst[0] = cv.u[0]; dst[1] = cv.u[1];
    } else {
        #pragma unroll
        for (int j = 0; j < 8; ++j)
            vbufT[((size_t)bn*64 + dg*8 + j)*PK + pp] = __float2bfloat16(s[j]*(1.f/81.f));
    }
}

// K5: MFMA leave-one-out sigmoid attention.
// Block: (bn, qtile of 64, ks half). LDS: Qs/Ks/Vs/Ps 64x128B XOR-swizzled.
__global__ __launch_bounds__(256) void k_attn3(const __hip_bfloat16* __restrict__ qb16,
        const __hip_bfloat16* __restrict__ kbufb, const __hip_bfloat16* __restrict__ vbufT,
        float* __restrict__ attnp) {
    __shared__ __align__(16) char smem[32768];
    char* Qs = smem;
    char* Ks = smem + 8192;
    char* Vs = smem + 16384;
    char* Ps = smem + 24576;
    int tid = threadIdx.x;
    int wid = tid >> 6, lane = tid & 63;
    int bid = blockIdx.x;
    int ks = bid & 1; bid >>= 1;
    int qt = bid % 36; int bn = bid / 36;
    int b = bn / NVIEW, n = bn % NVIEW;
    int p0 = qt*64;

    // stage Q (8KB contiguous, pre-swizzled source -> linear LDS)
    {
        const char* gq = (const char*)(qb16 + ((size_t)bn*PP + p0)*64);
        #pragma unroll
        for (int i = 0; i < 2; ++i) {
            int s = wid*2 + i;
            int lin = s*1024 + lane*16;
            int r = lin >> 7, c = (lin >> 4) & 7;
            int gof = (r<<7) + ((c ^ (r&7)) << 4);
            load_lds16(gq + gof, Qs + s*1024);
        }
    }
    int arow = wid*16 + (lane&15);   // QK A: key row
    int brow = lane&15;              // QK B: q row / PV B: d row base
    int gcol = lane>>4;              // granule sub-index
    int vrow = tid >> 2;             // V stage: d row
    int vc2 = (tid & 3) * 2;         // V stage: granule pair

    f32x4 oacc[4];
    #pragma unroll
    for (int i = 0; i < 4; ++i) oacc[i] = (f32x4){0,0,0,0};

    for (int mi = 0; mi < NVIEW-1; ++mi) {
        int m = mi + (mi >= n ? 1 : 0);
        int bnk = b*NVIEW + m;
        const char* gk = (const char*)(kbufb + (size_t)bnk*PK*64);
        const __hip_bfloat16* gv = vbufT + (size_t)bnk*64*PK;
        for (int kc = ks*2; kc < ks*2+2; ++kc) {
            __syncthreads();   // prev PV (reads Vs, Ps) done before restaging
            #pragma unroll
            for (int i = 0; i < 2; ++i) {
                int s = wid*2 + i;
                int lin = s*1024 + lane*16;
                int r = lin >> 7, c = (lin >> 4) & 7;
                int gof = (r<<7) + ((c ^ (r&7)) << 4);
                load_lds16(gk + (size_t)kc*8192 + gof, Ks + s*1024);
            }
            {
                const __hip_bfloat16* src = gv + vrow*PK + kc*64 + vc2*8;
                bf16x8 v0 = *(const bf16x8*)src;
                bf16x8 v1 = *(const bf16x8*)(src+8);
                *(bf16x8*)(Vs + vrow*128 + ((vc2 ^ (vrow&7))<<4)) = v0;
                *(bf16x8*)(Vs + vrow*128 + (((vc2+1) ^ (vrow&7))<<4)) = v1;
            }
            __syncthreads();
            // S^T = K . Q^T  (rows=16 keys of this wave, cols=64 q)
            f32x4 sacc[4];
            #pragma unroll
            for (int i = 0; i < 4; ++i) sacc[i] = (f32x4){0,0,0,0};
            #pragma unroll
            for (int kk = 0; kk < 2; ++kk) {
                int g = kk*4 + gcol;
                bf16x8 af = *(const bf16x8*)(Ks + arow*128 + ((g ^ (arow&7))<<4));
                #pragma unroll
                for (int nf = 0; nf < 4; ++nf) {
                    int q = nf*16 + brow;
                    bf16x8 bq = *(const bf16x8*)(Qs + q*128 + ((g ^ (q&7))<<4));
                    sacc[nf] = __builtin_amdgcn_mfma_f32_16x16x32_bf16(af, bq, sacc[nf], 0,0,0);
                }
            }
            // sigmoid -> Ps[q][key] bf16, swizzled; keys base..base+3 in one granule
            {
                int kbase = wid*16 + gcol*4;   // local key of regs 0..3
                #pragma unroll
                for (int nf = 0; nf < 4; ++nf) {
                    int q = nf*16 + brow;
                    ushort4 pu;
                    float e0 = __expf(-sacc[nf][0]*0.125f);
                    float e1 = __expf(-sacc[nf][1]*0.125f);
                    float e2 = __expf(-sacc[nf][2]*0.125f);
                    float e3 = __expf(-sacc[nf][3]*0.125f);
                    pu.x = f2bu(__builtin_amdgcn_rcpf(1.f+e0));
                    pu.y = f2bu(__builtin_amdgcn_rcpf(1.f+e1));
                    pu.z = f2bu(__builtin_amdgcn_rcpf(1.f+e2));
                    pu.w = f2bu(__builtin_amdgcn_rcpf(1.f+e3));
                    *(ushort4*)(Ps + q*128 + (((kbase>>3) ^ (q&7))<<4) + (kbase&7)*2) = pu;
                }
            }
            __syncthreads();
            // out += P . V  (rows=16 q of this wave, cols=64 d)
            #pragma unroll
            for (int kk = 0; kk < 2; ++kk) {
                int g = kk*4 + gcol;
                int qr = wid*16 + brow;
                bf16x8 pf = *(const bf16x8*)(Ps + qr*128 + ((g ^ (qr&7))<<4));
                #pragma unroll
                for (int nf = 0; nf < 4; ++nf) {
                    int d = nf*16 + brow;
                    bf16x8 vf = *(const bf16x8*)(Vs + d*128 + ((g ^ (d&7))<<4));
                    oacc[nf] = __builtin_amdgcn_mfma_f32_16x16x32_bf16(pf, vf, oacc[nf], 0,0,0);
                }
            }
        }
    }
    float* ab = attnp + (size_t)ks*SZ_ATTNP + ((size_t)bn*PP + p0)*64;
    #pragma unroll
    for (int nf = 0; nf < 4; ++nf) {
        #pragma unroll
        for (int r = 0; r < 4; ++r) {
            int q = wid*16 + gcol*4 + r;
            int d = nf*16 + brow;
            ab[(size_t)q*64 + d] = oacc[nf][r];
        }
    }
}

// K6: out = relu(W2 relu(W1 relu(attn0+attn1 + scale*xv) + b1) + b2)
__global__ __launch_bounds__(256) void k_out(const float* __restrict__ attnp,
        const float* __restrict__ qkv, const float* __restrict__ scales,
        const float* __restrict__ w1, const float* __restrict__ b1,
        const float* __restrict__ w2, const float* __restrict__ b2,
        float* __restrict__ out) {
    int bx = blockIdx.x;
    int pb = bx % 9; int bn = bx / 9;
    int p = pb*256 + threadIdx.x;
    int n = bn % NVIEW;
    float sc = scales[n];
    const float* a0 = attnp + ((size_t)bn*PP + p)*HIDP;
    const float* a1 = a0 + SZ_ATTNP;
    const float* xvb = qkv + ((size_t)bn*OC + 2*HIDP)*PP;
    float res[64];
    #pragma unroll
    for (int i = 0; i < 64; ++i)
        res[i] = fmaxf(a0[i] + a1[i] + sc*xvb[i*PP+p], 0.f);
    float t[64];
    #pragma unroll
    for (int o = 0; o < 64; ++o) {
        float a = b1[o];
        #pragma unroll
        for (int i = 0; i < 64; ++i) a += w1[o*64+i]*res[i];
        t[o] = fmaxf(a, 0.f);
    }
    float* ob = out + (size_t)bn*HIDP*PP;
    #pragma unroll
    for (int o = 0; o < 64; ++o) {
        float a = b2[o];
        #pragma unroll
        for (int i = 0; i < 64; ++i) a += w2[o*64+i]*t[i];
        ob[o*PP+p] = fmaxf(a, 0.f);
    }
}

extern "C" void kernel_launch(void* const* d_in, const int* in_sizes, int n_in,
                              void* d_out, int out_size, void* d_ws, size_t ws_size,
                              hipStream_t stream) {
    (void)in_sizes; (void)n_in; (void)out_size; (void)ws_size;
    const float* x      = (const float*)d_in[0];
    const float* pa_w1  = (const float*)d_in[1];
    const float* pa_b1  = (const float*)d_in[2];
    const float* pa_w2  = (const float*)d_in[3];
    const float* pa_b2  = (const float*)d_in[4];
    const float* pa_w3  = (const float*)d_in[5];
    const float* pa_b3  = (const float*)d_in[6];
    const float* pa_cw1 = (const float*)d_in[7];
    const float* pa_cb1 = (const float*)d_in[8];
    const float* pa_cw2 = (const float*)d_in[9];
    const float* pa_cb2 = (const float*)d_in[10];
    const float* kv_w   = (const float*)d_in[11];
    const float* kv_b   = (const float*)d_in[12];
    const float* out_w1 = (const float*)d_in[13];
    const float* out_b1 = (const float*)d_in[14];
    const float* out_w2 = (const float*)d_in[15];
    const float* out_b2 = (const float*)d_in[16];
    const float* scales = (const float*)d_in[17];
    float* out = (float*)d_out;
    float* ws  = (float*)d_ws;

    __hip_bfloat16* weffb = (__hip_bfloat16*)(ws + OFF_WEFFB);
    float* beff = ws + OFF_BEFF;
    __hip_bfloat16* cw2b = (__hip_bfloat16*)(ws + OFF_CW2B);
    float* wkv2 = ws + OFF_WKV;
    __hip_bfloat16* padxT = (__hip_bfloat16*)(ws + OFF_PADXT);
    __hip_bfloat16* qb16  = (__hip_bfloat16*)(ws + OFF_QB16);
    __hip_bfloat16* kbufb = (__hip_bfloat16*)(ws + OFF_KB16);
    __hip_bfloat16* vbufT = (__hip_bfloat16*)(ws + OFF_VB16T);
    __hip_bfloat16* hidbt = (__hip_bfloat16*)(ws + OFF_SHARED);
    float* convtmp = ws + OFF_SHARED;
    float* attnp   = ws + OFF_SHARED;
    float* qkv  = ws + OFF_QKV;

    k_fold<<<3*OC, CIN*9, 0, stream>>>(pa_cw1, pa_cb1, pa_w1, pa_b1,
                                       pa_w2, pa_b2, pa_w3, pa_b3, weffb, beff);
    k_wkv<<<(SZ_WKV+255)/256, 256, 0, stream>>>(kv_w, wkv2);
    k_wcvt<<<(OC*OC+255)/256, 256, 0, stream>>>(pa_cw2, cw2b);
    k_padxT<<<(BN*PADA+255)/256, 256, 0, stream>>>(x, padxT);
    k_gemm1<<<dim3(NTOT/128, 3), 256, 0, stream>>>(weffb, padxT, beff, hidbt);
    k_gemm2<<<dim3(NTOT/128, 3), 256, 0, stream>>>(cw2b, hidbt, pa_cb2, qkv, qb16);
    k_kvconv<<<BN*2*8*9, 256, 0, stream>>>(qkv, wkv2, kv_b, convtmp);
    k_pool<<<BN*2*PK*8/256, 256, 0, stream>>>(convtmp, kbufb, vbufT);
    k_attn3<<<BN*36*2, 256, 0, stream>>>(qb16, kbufb, vbufT, attnp);
    k_out<<<BN*9, 256, 0, stream>>>(attnp, qkv, scales, out_w1, out_b1,
                                    out_w2, out_b2, out);
}

// Round 5
// 207.176 us; speedup vs baseline: 36.6461x; 1.6148x over previous
//
#include <hip/hip_runtime.h>
#include <hip/hip_bf16.h>
#include <math.h>

#define BB 2
#define NVIEW 6
#define BN 12
#define CIN 64
#define HH 48
#define WW 48
#define PP (HH*WW)        // 2304
#define OC 192
#define HPA 192
#define HIDP 64
#define KHW 16
#define PK 256
#define PADW 54
#define PADA (PADW*PADW)  // 2916
#define NTOT (BN*PP)      // 27648
#define K1 1728           // 27 taps * 64 ic
#define KVPW 50
#define KVPA (KVPW*KVPW)  // 2500

typedef __attribute__((ext_vector_type(8))) short bf16x8;
typedef __attribute__((ext_vector_type(4))) float f32x4;

// ---- workspace layout (float elements) ----
#define OFF_WEFFB 0
#define SZ_WEFFB_FL (OC*K1/2)              // 165888
#define OFF_BEFF (OFF_WEFFB + SZ_WEFFB_FL)
#define SZ_BEFF 256
#define OFF_CW2B (OFF_BEFF + SZ_BEFF)
#define SZ_CW2B_FL (OC*OC/2)               // 18432
#define OFF_WKVB (OFF_CW2B + SZ_CW2B_FL)
#define SZ_WKVB_FL (64*576/2)              // 18432
#define OFF_PADXT (OFF_WKVB + SZ_WKVB_FL)
#define SZ_PADXT_FL (BN*PADA*64/2)         // 1119744
#define OFF_QB16 (OFF_PADXT + SZ_PADXT_FL)
#define SZ_QB16_FL (BN*PP*64/2)            // 884736
#define OFF_KB16 (OFF_QB16 + SZ_QB16_FL)
#define SZ_KB16_FL (BN*PK*64/2)            // 98304
#define OFF_VB16T (OFF_KB16 + SZ_KB16_FL)
#define SZ_VB16T_FL (BN*64*PK/2)           // 98304
#define OFF_KVPAD (OFF_VB16T + SZ_VB16T_FL)
#define SZ_KVPAD_FL (BN*2*KVPA*64/2)       // 1920000
#define OFF_CONVB (OFF_KVPAD + SZ_KVPAD_FL)
#define SZ_CONVB_FL (BN*2*PP*64/2)         // 1769472
#define OFF_ATTNP (OFF_CONVB + SZ_CONVB_FL) // also aliases hidbt (gemm1->gemm2)
#define SZ_ATTNP (BN*PP*HIDP)              // 1769472 per partial, 2 partials
#define OFF_XVF (OFF_ATTNP + 2*SZ_ATTNP)
#define SZ_XVF (BN*HIDP*PP)                // 1769472 fp32

__device__ __forceinline__ void load_lds16(const void* g, void* l) {
    __builtin_amdgcn_global_load_lds(
        (const __attribute__((address_space(1))) unsigned int*)g,
        (__attribute__((address_space(3))) unsigned int*)l, 16, 0, 0);
}

__device__ __forceinline__ unsigned short f2bu(float f) {
    __hip_bfloat16 h = __float2bfloat16(f);
    return *(unsigned short*)&h;
}

// K1: fold pa_cw1 (192x576) into 3 effective dilated convs -> bf16 [oc][r*576+tap*64+ic]
__global__ void k_fold(const float* __restrict__ cw1, const float* __restrict__ cb1,
                       const float* __restrict__ w1, const float* __restrict__ b1,
                       const float* __restrict__ w2, const float* __restrict__ b2,
                       const float* __restrict__ w3, const float* __restrict__ b3,
                       __hip_bfloat16* __restrict__ weffb, float* __restrict__ beff) {
    int r = blockIdx.x / OC;
    int o = blockIdx.x % OC;
    int t = threadIdx.x;                   // ic*9 + tap
    int ic = t / 9, tap = t % 9;
    const float* w = (r==0) ? w1 : (r==1) ? w2 : w3;
    float acc = 0.f;
    for (int c = 0; c < HPA; ++c)
        acc += cw1[o*(HPA*3) + r*HPA + c] * w[c*(CIN*9) + t];
    weffb[(size_t)o*K1 + r*576 + tap*64 + ic] = __float2bfloat16(acc);
    if (r == 0 && t == 0) {
        float bacc = cb1[o];
        for (int rr = 0; rr < 3; ++rr) {
            const float* bb = (rr==0)?b1:(rr==1)?b2:b3;
            for (int c = 0; c < HPA; ++c)
                bacc += cw1[o*(HPA*3) + rr*HPA + c] * bb[c];
        }
        beff[o] = bacc;
    }
}

// K1b: kv_w [oc][ic][tap] -> bf16 [oc][tap*64+ic]
__global__ void k_wkvb(const float* __restrict__ kvw, __hip_bfloat16* __restrict__ wkvb) {
    int idx = blockIdx.x*256 + threadIdx.x;
    if (idx >= 64*576) return;
    int oc = idx / 576, rest = idx % 576;
    int tap = rest / 64, ic = rest % 64;
    wkvb[idx] = __float2bfloat16(kvw[(oc*64 + ic)*9 + tap]);
}

// K1c: cw2 -> bf16 [oc][ic]
__global__ void k_wcvt(const float* __restrict__ cw2, __hip_bfloat16* __restrict__ cw2b) {
    int idx = blockIdx.x*256 + threadIdx.x;
    if (idx < OC*OC) cw2b[idx] = __float2bfloat16(cw2[idx]);
}

// K1d: channels-last padded x, bf16: padxT[bn][spos(54x54)][ic(64)]
__global__ void k_padxT(const float* __restrict__ x, __hip_bfloat16* __restrict__ padxT) {
    int idx = blockIdx.x*256 + threadIdx.x;
    if (idx >= BN*PADA) return;
    int spos = idx % PADA; int bn = idx / PADA;
    int sy = spos / PADW, sx = spos % PADW;
    __hip_bfloat16* dst = padxT + (size_t)idx*64;
    if (sy >= 3 && sy < 51 && sx >= 3 && sx < 51) {
        const float* src = x + (size_t)bn*CIN*PP + (sy-3)*WW + (sx-3);
        #pragma unroll 8
        for (int ic = 0; ic < 64; ++ic) dst[ic] = __float2bfloat16(src[ic*PP]);
    } else {
        #pragma unroll 8
        for (int ic = 0; ic < 64; ++ic) dst[ic] = __float2bfloat16(0.f);
    }
}

// K1e: zero kvpad (halo); interior overwritten by gemm2
__global__ void k_zero(__hip_bfloat16* __restrict__ kvpad) {
    size_t idx = ((size_t)blockIdx.x*256 + threadIdx.x)*8;
    bf16x8 z = (bf16x8){0,0,0,0,0,0,0,0};
    *(bf16x8*)(kvpad + idx) = z;
}

// GEMM1 (implicit dilated conv): hid_bt[n][oc] = relu( weffb[oc][k] * B[k][n] + beff )
__global__ __launch_bounds__(256) void k_gemm1(const __hip_bfloat16* __restrict__ wA,
        const __hip_bfloat16* __restrict__ pxT, const float* __restrict__ beff,
        __hip_bfloat16* __restrict__ hidbt) {
    __shared__ __align__(16) char smem[24576];   // A [64][64] @0, B [128][64] @8192
    int tid = threadIdx.x;
    int wid = tid >> 6, lane = tid & 63;
    int tileN = blockIdx.x * 128, tileM = blockIdx.y * 64;

    size_t gbase[6];
    #pragma unroll
    for (int s2 = 0; s2 < 6; ++s2) {
        int seg = wid*6 + s2;
        if (seg < 8) {
            int row = seg*8 + (lane>>3);
            gbase[s2] = (size_t)(tileM + row)*K1 + (lane&7)*8;
        } else {
            int n = tileN + (seg-8)*8 + (lane>>3);
            int bn = n / PP, p = n % PP;
            int py = p / WW, px = p % WW;
            gbase[s2] = ((size_t)bn*PADA + (py+3)*PADW + (px+3))*64 + (lane&7)*8;
        }
    }
    int wr = wid >> 1, wc = wid & 1;
    int aoff[2], boff[4];
    #pragma unroll
    for (int m = 0; m < 2; ++m)
        aoff[m] = ((wr*32 + m*16 + (lane&15))*64 + (lane>>4)*8)*2;
    #pragma unroll
    for (int nf = 0; nf < 4; ++nf)
        boff[nf] = 8192 + ((wc*64 + nf*16 + (lane&15))*64 + (lane>>4)*8)*2;

    f32x4 acc[2][4];
    #pragma unroll
    for (int m = 0; m < 2; ++m)
        #pragma unroll
        for (int nf = 0; nf < 4; ++nf) acc[m][nf] = (f32x4){0.f,0.f,0.f,0.f};

    for (int kt = 0; kt < 27; ++kt) {
        int r_ = kt / 9, tap = kt - r_*9;
        int dy = tap/3 - 1, dx = tap%3 - 1;
        int doff = (r_+1)*(dy*PADW + dx);
        __syncthreads();
        #pragma unroll
        for (int s2 = 0; s2 < 6; ++s2) {
            int seg = wid*6 + s2;
            const __hip_bfloat16* g = (seg < 8) ? wA + gbase[s2] + kt*64
                                                : pxT + gbase[s2] + (size_t)doff*64;
            load_lds16(g, smem + seg*1024);
        }
        __syncthreads();
        bf16x8 a[2][2], b[4][2];
        #pragma unroll
        for (int m = 0; m < 2; ++m)
            #pragma unroll
            for (int kk = 0; kk < 2; ++kk)
                a[m][kk] = *(const bf16x8*)(smem + aoff[m] + kk*64);
        #pragma unroll
        for (int nf = 0; nf < 4; ++nf)
            #pragma unroll
            for (int kk = 0; kk < 2; ++kk)
                b[nf][kk] = *(const bf16x8*)(smem + boff[nf] + kk*64);
        #pragma unroll
        for (int kk = 0; kk < 2; ++kk)
            #pragma unroll
            for (int m = 0; m < 2; ++m)
                #pragma unroll
                for (int nf = 0; nf < 4; ++nf)
                    acc[m][nf] = __builtin_amdgcn_mfma_f32_16x16x32_bf16(
                        a[m][kk], b[nf][kk], acc[m][nf], 0, 0, 0);
    }
    #pragma unroll
    for (int m = 0; m < 2; ++m) {
        int rbase = tileM + wr*32 + m*16 + (lane>>4)*4;
        float4 bz = *(const float4*)&beff[rbase];
        #pragma unroll
        for (int nf = 0; nf < 4; ++nf) {
            int col = tileN + wc*64 + nf*16 + (lane&15);
            union { ushort4 u; __hip_bfloat16 h[4]; } cv;
            cv.h[0] = __float2bfloat16(fmaxf(acc[m][nf][0] + bz.x, 0.f));
            cv.h[1] = __float2bfloat16(fmaxf(acc[m][nf][1] + bz.y, 0.f));
            cv.h[2] = __float2bfloat16(fmaxf(acc[m][nf][2] + bz.z, 0.f));
            cv.h[3] = __float2bfloat16(fmaxf(acc[m][nf][3] + bz.w, 0.f));
            *(ushort4*)&hidbt[(size_t)col*OC + rbase] = cv.u;
        }
    }
}

// GEMM2: epilogue routes by tileM: q->qb16 [n][d]; k,v->kvpad bf16 channels-last; v also fp32 xvf
__global__ __launch_bounds__(256) void k_gemm2(const __hip_bfloat16* __restrict__ wA,
        const __hip_bfloat16* __restrict__ Bt, const float* __restrict__ cb2,
        float* __restrict__ xvf, __hip_bfloat16* __restrict__ qb16,
        __hip_bfloat16* __restrict__ kvpad) {
    __shared__ __align__(16) char smem[24576];
    int tid = threadIdx.x;
    int wid = tid >> 6, lane = tid & 63;
    int tileN = blockIdx.x * 128, tileM = blockIdx.y * 64;
    size_t gbase[6]; const __hip_bfloat16* gsrc[6];
    #pragma unroll
    for (int s2 = 0; s2 < 6; ++s2) {
        int seg = wid*6 + s2;
        if (seg < 8) {
            int row = seg*8 + (lane>>3);
            gbase[s2] = (size_t)(tileM + row)*OC + (lane&7)*8;
            gsrc[s2] = wA;
        } else {
            int n = tileN + (seg-8)*8 + (lane>>3);
            gbase[s2] = (size_t)n*OC + (lane&7)*8;
            gsrc[s2] = Bt;
        }
    }
    int wr = wid >> 1, wc = wid & 1;
    int aoff[2], boff[4];
    #pragma unroll
    for (int m = 0; m < 2; ++m)
        aoff[m] = ((wr*32 + m*16 + (lane&15))*64 + (lane>>4)*8)*2;
    #pragma unroll
    for (int nf = 0; nf < 4; ++nf)
        boff[nf] = 8192 + ((wc*64 + nf*16 + (lane&15))*64 + (lane>>4)*8)*2;
    f32x4 acc[2][4];
    #pragma unroll
    for (int m = 0; m < 2; ++m)
        #pragma unroll
        for (int nf = 0; nf < 4; ++nf) acc[m][nf] = (f32x4){0.f,0.f,0.f,0.f};

    for (int kt = 0; kt < 3; ++kt) {
        __syncthreads();
        #pragma unroll
        for (int s2 = 0; s2 < 6; ++s2)
            load_lds16(gsrc[s2] + gbase[s2] + kt*64, smem + (wid*6+s2)*1024);
        __syncthreads();
        bf16x8 a[2][2], b[4][2];
        #pragma unroll
        for (int m = 0; m < 2; ++m)
            #pragma unroll
            for (int kk = 0; kk < 2; ++kk)
                a[m][kk] = *(const bf16x8*)(smem + aoff[m] + kk*64);
        #pragma unroll
        for (int nf = 0; nf < 4; ++nf)
            #pragma unroll
            for (int kk = 0; kk < 2; ++kk)
                b[nf][kk] = *(const bf16x8*)(smem + boff[nf] + kk*64);
        #pragma unroll
        for (int kk = 0; kk < 2; ++kk)
            #pragma unroll
            for (int m = 0; m < 2; ++m)
                #pragma unroll
                for (int nf = 0; nf < 4; ++nf)
                    acc[m][nf] = __builtin_amdgcn_mfma_f32_16x16x32_bf16(
                        a[m][kk], b[nf][kk], acc[m][nf], 0, 0, 0);
    }
    #pragma unroll
    for (int m = 0; m < 2; ++m) {
        int rbase = tileM + wr*32 + m*16 + (lane>>4)*4;
        float4 cz = *(const float4*)&cb2[rbase];
        #pragma unroll
        for (int nf = 0; nf < 4; ++nf) {
            int col = tileN + wc*64 + nf*16 + (lane&15);
            int bn = col / PP, p = col % PP;
            float v0 = fmaxf(acc[m][nf][0] + cz.x, 0.f);
            float v1 = fmaxf(acc[m][nf][1] + cz.y, 0.f);
            float v2 = fmaxf(acc[m][nf][2] + cz.z, 0.f);
            float v3 = fmaxf(acc[m][nf][3] + cz.w, 0.f);
            ushort4 bv;
            bv.x = f2bu(v0); bv.y = f2bu(v1); bv.z = f2bu(v2); bv.w = f2bu(v3);
            if (tileM == 0) {
                *(ushort4*)&qb16[(size_t)col*64 + rbase] = bv;
            } else {
                int kv = (tileM == 128) ? 1 : 0;
                int py = p / WW, px = p % WW;
                int d = rbase - tileM;
                *(ushort4*)&kvpad[((size_t)(bn*2+kv)*KVPA + (py+1)*KVPW + px+1)*64 + d] = bv;
                if (kv == 1) {
                    float* dst = xvf + (size_t)bn*HIDP*PP + (size_t)d*PP + p;
                    dst[0*PP] = v0; dst[1*PP] = v1; dst[2*PP] = v2; dst[3*PP] = v3;
                }
            }
        }
    }
}

// K4a: MFMA conv3x3 64->64 on kvpad -> convb bf16 [bn2][p][64]
__global__ __launch_bounds__(256) void k_kvgemm(const __hip_bfloat16* __restrict__ wA,
        const __hip_bfloat16* __restrict__ kvpad, const float* __restrict__ kvb,
        __hip_bfloat16* __restrict__ convb) {
    __shared__ __align__(16) char smem[24576];
    int tid = threadIdx.x;
    int wid = tid >> 6, lane = tid & 63;
    int tileN = blockIdx.x * 128;
    int bn2 = tileN / PP, p0 = tileN % PP;

    size_t gbase[6];
    #pragma unroll
    for (int s2 = 0; s2 < 6; ++s2) {
        int seg = wid*6 + s2;
        if (seg < 8) {
            int row = seg*8 + (lane>>3);
            gbase[s2] = (size_t)row*576 + (lane&7)*8;
        } else {
            int p = p0 + (seg-8)*8 + (lane>>3);
            int py = p / WW, px = p % WW;
            gbase[s2] = ((size_t)bn2*KVPA + (py+1)*KVPW + px+1)*64 + (lane&7)*8;
        }
    }
    int wr = wid >> 1, wc = wid & 1;
    int aoff[2], boff[4];
    #pragma unroll
    for (int m = 0; m < 2; ++m)
        aoff[m] = ((wr*32 + m*16 + (lane&15))*64 + (lane>>4)*8)*2;
    #pragma unroll
    for (int nf = 0; nf < 4; ++nf)
        boff[nf] = 8192 + ((wc*64 + nf*16 + (lane&15))*64 + (lane>>4)*8)*2;

    f32x4 acc[2][4];
    #pragma unroll
    for (int m = 0; m < 2; ++m)
        #pragma unroll
        for (int nf = 0; nf < 4; ++nf) acc[m][nf] = (f32x4){0.f,0.f,0.f,0.f};

    for (int kt = 0; kt < 9; ++kt) {
        int dy = kt/3 - 1, dx = kt%3 - 1;
        int doff = dy*KVPW + dx;
        __syncthreads();
        #pragma unroll
        for (int s2 = 0; s2 < 6; ++s2) {
            int seg = wid*6 + s2;
            const __hip_bfloat16* g = (seg < 8) ? wA + gbase[s2] + kt*64
                                                : kvpad + gbase[s2] + (size_t)doff*64;
            load_lds16(g, smem + seg*1024);
        }
        __syncthreads();
        bf16x8 a[2][2], b[4][2];
        #pragma unroll
        for (int m = 0; m < 2; ++m)
            #pragma unroll
            for (int kk = 0; kk < 2; ++kk)
                a[m][kk] = *(const bf16x8*)(smem + aoff[m] + kk*64);
        #pragma unroll
        for (int nf = 0; nf < 4; ++nf)
            #pragma unroll
            for (int kk = 0; kk < 2; ++kk)
                b[nf][kk] = *(const bf16x8*)(smem + boff[nf] + kk*64);
        #pragma unroll
        for (int kk = 0; kk < 2; ++kk)
            #pragma unroll
            for (int m = 0; m < 2; ++m)
                #pragma unroll
                for (int nf = 0; nf < 4; ++nf)
                    acc[m][nf] = __builtin_amdgcn_mfma_f32_16x16x32_bf16(
                        a[m][kk], b[nf][kk], acc[m][nf], 0, 0, 0);
    }
    #pragma unroll
    for (int m = 0; m < 2; ++m) {
        int rbase = wr*32 + m*16 + (lane>>4)*4;
        float4 bz = *(const float4*)&kvb[rbase];
        #pragma unroll
        for (int nf = 0; nf < 4; ++nf) {
            int col = p0 + wc*64 + nf*16 + (lane&15);
            ushort4 cv;
            cv.x = f2bu(fmaxf(acc[m][nf][0] + bz.x, 0.f));
            cv.y = f2bu(fmaxf(acc[m][nf][1] + bz.y, 0.f));
            cv.z = f2bu(fmaxf(acc[m][nf][2] + bz.z, 0.f));
            cv.w = f2bu(fmaxf(acc[m][nf][3] + bz.w, 0.f));
            *(ushort4*)&convb[((size_t)bn2*PP + col)*64 + rbase] = cv;
        }
    }
}

// K4b: 3x3 avgpool on convb -> kbufb bf16 [bn][k][d], vbufT bf16 [bn][d][k]
__global__ __launch_bounds__(256) void k_pool(const __hip_bfloat16* __restrict__ convb,
        __hip_bfloat16* __restrict__ kbufb, __hip_bfloat16* __restrict__ vbufT) {
    int idx = blockIdx.x*256 + threadIdx.x;
    int dg = idx % 8; idx /= 8;
    int pp = idx % PK; idx /= PK;
    int bn2 = idx;                       // bn*2+kv
    int kv = bn2 & 1, bn = bn2 >> 1;
    int qy = pp / KHW, qx = pp % KHW;
    float s[8] = {0,0,0,0,0,0,0,0};
    const __hip_bfloat16* base = convb + (size_t)bn2*PP*64 + dg*8;
    #pragma unroll
    for (int sy = 0; sy < 3; ++sy)
        #pragma unroll
        for (int sx = 0; sx < 3; ++sx) {
            union { bf16x8 v; unsigned short h[8]; } c;
            c.v = *(const bf16x8*)(base + ((size_t)(qy*3+sy)*WW + qx*3+sx)*64);
            #pragma unroll
            for (int j = 0; j < 8; ++j) {
                unsigned int u = ((unsigned int)c.h[j]) << 16;
                s[j] += *(float*)&u;
            }
        }
    if (kv == 0) {
        union { ushort4 u[2]; unsigned short h[8]; } cv;
        #pragma unroll
        for (int j = 0; j < 8; ++j) cv.h[j] = f2bu(s[j] * (1.f/9.f));
        ushort4* dst = (ushort4*)(kbufb + ((size_t)bn*PK + pp)*64 + dg*8);
        dst[0] = cv.u[0]; dst[1] = cv.u[1];
    } else {
        #pragma unroll
        for (int j = 0; j < 8; ++j)
            vbufT[((size_t)bn*64 + dg*8 + j)*PK + pp] = __float2bfloat16(s[j]*(1.f/81.f));
    }
}

// K5: MFMA leave-one-out sigmoid attention.
__global__ __launch_bounds__(256) void k_attn3(const __hip_bfloat16* __restrict__ qb16,
        const __hip_bfloat16* __restrict__ kbufb, const __hip_bfloat16* __restrict__ vbufT,
        float* __restrict__ attnp) {
    __shared__ __align__(16) char smem[32768];
    char* Qs = smem;
    char* Ks = smem + 8192;
    char* Vs = smem + 16384;
    char* Ps = smem + 24576;
    int tid = threadIdx.x;
    int wid = tid >> 6, lane = tid & 63;
    int bid = blockIdx.x;
    int ks = bid & 1; bid >>= 1;
    int qt = bid % 36; int bn = bid / 36;
    int b = bn / NVIEW, n = bn % NVIEW;
    int p0 = qt*64;

    {
        const char* gq = (const char*)(qb16 + ((size_t)bn*PP + p0)*64);
        #pragma unroll
        for (int i = 0; i < 2; ++i) {
            int s = wid*2 + i;
            int lin = s*1024 + lane*16;
            int r = lin >> 7, c = (lin >> 4) & 7;
            int gof = (r<<7) + ((c ^ (r&7)) << 4);
            load_lds16(gq + gof, Qs + s*1024);
        }
    }
    int arow = wid*16 + (lane&15);
    int brow = lane&15;
    int gcol = lane>>4;
    int vrow = tid >> 2;
    int vc2 = (tid & 3) * 2;

    f32x4 oacc[4];
    #pragma unroll
    for (int i = 0; i < 4; ++i) oacc[i] = (f32x4){0,0,0,0};

    for (int mi = 0; mi < NVIEW-1; ++mi) {
        int m = mi + (mi >= n ? 1 : 0);
        int bnk = b*NVIEW + m;
        const char* gk = (const char*)(kbufb + (size_t)bnk*PK*64);
        const __hip_bfloat16* gv = vbufT + (size_t)bnk*64*PK;
        for (int kc = ks*2; kc < ks*2+2; ++kc) {
            __syncthreads();
            #pragma unroll
            for (int i = 0; i < 2; ++i) {
                int s = wid*2 + i;
                int lin = s*1024 + lane*16;
                int r = lin >> 7, c = (lin >> 4) & 7;
                int gof = (r<<7) + ((c ^ (r&7)) << 4);
                load_lds16(gk + (size_t)kc*8192 + gof, Ks + s*1024);
            }
            {
                const __hip_bfloat16* src = gv + vrow*PK + kc*64 + vc2*8;
                bf16x8 v0 = *(const bf16x8*)src;
                bf16x8 v1 = *(const bf16x8*)(src+8);
                *(bf16x8*)(Vs + vrow*128 + ((vc2 ^ (vrow&7))<<4)) = v0;
                *(bf16x8*)(Vs + vrow*128 + (((vc2+1) ^ (vrow&7))<<4)) = v1;
            }
            __syncthreads();
            f32x4 sacc[4];
            #pragma unroll
            for (int i = 0; i < 4; ++i) sacc[i] = (f32x4){0,0,0,0};
            #pragma unroll
            for (int kk = 0; kk < 2; ++kk) {
                int g = kk*4 + gcol;
                bf16x8 af = *(const bf16x8*)(Ks + arow*128 + ((g ^ (arow&7))<<4));
                #pragma unroll
                for (int nf = 0; nf < 4; ++nf) {
                    int q = nf*16 + brow;
                    bf16x8 bq = *(const bf16x8*)(Qs + q*128 + ((g ^ (q&7))<<4));
                    sacc[nf] = __builtin_amdgcn_mfma_f32_16x16x32_bf16(af, bq, sacc[nf], 0,0,0);
                }
            }
            {
                int kbase = wid*16 + gcol*4;
                #pragma unroll
                for (int nf = 0; nf < 4; ++nf) {
                    int q = nf*16 + brow;
                    ushort4 pu;
                    float e0 = __expf(-sacc[nf][0]*0.125f);
                    float e1 = __expf(-sacc[nf][1]*0.125f);
                    float e2 = __expf(-sacc[nf][2]*0.125f);
                    float e3 = __expf(-sacc[nf][3]*0.125f);
                    pu.x = f2bu(__builtin_amdgcn_rcpf(1.f+e0));
                    pu.y = f2bu(__builtin_amdgcn_rcpf(1.f+e1));
                    pu.z = f2bu(__builtin_amdgcn_rcpf(1.f+e2));
                    pu.w = f2bu(__builtin_amdgcn_rcpf(1.f+e3));
                    *(ushort4*)(Ps + q*128 + (((kbase>>3) ^ (q&7))<<4) + (kbase&7)*2) = pu;
                }
            }
            __syncthreads();
            #pragma unroll
            for (int kk = 0; kk < 2; ++kk) {
                int g = kk*4 + gcol;
                int qr = wid*16 + brow;
                bf16x8 pf = *(const bf16x8*)(Ps + qr*128 + ((g ^ (qr&7))<<4));
                #pragma unroll
                for (int nf = 0; nf < 4; ++nf) {
                    int d = nf*16 + brow;
                    bf16x8 vf = *(const bf16x8*)(Vs + d*128 + ((g ^ (d&7))<<4));
                    oacc[nf] = __builtin_amdgcn_mfma_f32_16x16x32_bf16(pf, vf, oacc[nf], 0,0,0);
                }
            }
        }
    }
    float* ab = attnp + (size_t)ks*SZ_ATTNP + ((size_t)bn*PP + p0)*64;
    #pragma unroll
    for (int nf = 0; nf < 4; ++nf) {
        #pragma unroll
        for (int r = 0; r < 4; ++r) {
            int q = wid*16 + gcol*4 + r;
            int d = nf*16 + brow;
            ab[(size_t)q*64 + d] = oacc[nf][r];
        }
    }
}

// K6: out = relu(W2 relu(W1 relu(attn0+attn1 + scale*xv) + b1) + b2)
__global__ __launch_bounds__(256) void k_out(const float* __restrict__ attnp,
        const float* __restrict__ xvf, const float* __restrict__ scales,
        const float* __restrict__ w1, const float* __restrict__ b1,
        const float* __restrict__ w2, const float* __restrict__ b2,
        float* __restrict__ out) {
    int bx = blockIdx.x;
    int pb = bx % 9; int bn = bx / 9;
    int p = pb*256 + threadIdx.x;
    int n = bn % NVIEW;
    float sc = scales[n];
    const float* a0 = attnp + ((size_t)bn*PP + p)*HIDP;
    const float* a1 = a0 + SZ_ATTNP;
    const float* xvb = xvf + (size_t)bn*HIDP*PP;
    float res[64];
    #pragma unroll
    for (int i = 0; i < 64; ++i)
        res[i] = fmaxf(a0[i] + a1[i] + sc*xvb[i*PP+p], 0.f);
    float t[64];
    #pragma unroll
    for (int o = 0; o < 64; ++o) {
        float a = b1[o];
        #pragma unroll
        for (int i = 0; i < 64; ++i) a += w1[o*64+i]*res[i];
        t[o] = fmaxf(a, 0.f);
    }
    float* ob = out + (size_t)bn*HIDP*PP;
    #pragma unroll
    for (int o = 0; o < 64; ++o) {
        float a = b2[o];
        #pragma unroll
        for (int i = 0; i < 64; ++i) a += w2[o*64+i]*t[i];
        ob[o*PP+p] = fmaxf(a, 0.f);
    }
}

extern "C" void kernel_launch(void* const* d_in, const int* in_sizes, int n_in,
                              void* d_out, int out_size, void* d_ws, size_t ws_size,
                              hipStream_t stream) {
    (void)in_sizes; (void)n_in; (void)out_size; (void)ws_size;
    const float* x      = (const float*)d_in[0];
    const float* pa_w1  = (const float*)d_in[1];
    const float* pa_b1  = (const float*)d_in[2];
    const float* pa_w2  = (const float*)d_in[3];
    const float* pa_b2  = (const float*)d_in[4];
    const float* pa_w3  = (const float*)d_in[5];
    const float* pa_b3  = (const float*)d_in[6];
    const float* pa_cw1 = (const float*)d_in[7];
    const float* pa_cb1 = (const float*)d_in[8];
    const float* pa_cw2 = (const float*)d_in[9];
    const float* pa_cb2 = (const float*)d_in[10];
    const float* kv_w   = (const float*)d_in[11];
    const float* kv_b   = (const float*)d_in[12];
    const float* out_w1 = (const float*)d_in[13];
    const float* out_b1 = (const float*)d_in[14];
    const float* out_w2 = (const float*)d_in[15];
    const float* out_b2 = (const float*)d_in[16];
    const float* scales = (const float*)d_in[17];
    float* out = (float*)d_out;
    float* ws  = (float*)d_ws;

    __hip_bfloat16* weffb = (__hip_bfloat16*)(ws + OFF_WEFFB);
    float* beff = ws + OFF_BEFF;
    __hip_bfloat16* cw2b  = (__hip_bfloat16*)(ws + OFF_CW2B);
    __hip_bfloat16* wkvb  = (__hip_bfloat16*)(ws + OFF_WKVB);
    __hip_bfloat16* padxT = (__hip_bfloat16*)(ws + OFF_PADXT);
    __hip_bfloat16* qb16  = (__hip_bfloat16*)(ws + OFF_QB16);
    __hip_bfloat16* kbufb = (__hip_bfloat16*)(ws + OFF_KB16);
    __hip_bfloat16* vbufT = (__hip_bfloat16*)(ws + OFF_VB16T);
    __hip_bfloat16* kvpad = (__hip_bfloat16*)(ws + OFF_KVPAD);
    __hip_bfloat16* convb = (__hip_bfloat16*)(ws + OFF_CONVB);
    __hip_bfloat16* hidbt = (__hip_bfloat16*)(ws + OFF_ATTNP);  // alias (pre-attn)
    float* attnp = ws + OFF_ATTNP;
    float* xvf   = ws + OFF_XVF;

    k_fold<<<3*OC, CIN*9, 0, stream>>>(pa_cw1, pa_cb1, pa_w1, pa_b1,
                                       pa_w2, pa_b2, pa_w3, pa_b3, weffb, beff);
    k_wkvb<<<(64*576+255)/256, 256, 0, stream>>>(kv_w, wkvb);
    k_wcvt<<<(OC*OC+255)/256, 256, 0, stream>>>(pa_cw2, cw2b);
    k_padxT<<<(BN*PADA+255)/256, 256, 0, stream>>>(x, padxT);
    k_zero<<<(BN*2*KVPA*64/8)/256, 256, 0, stream>>>(kvpad);
    k_gemm1<<<dim3(NTOT/128, 3), 256, 0, stream>>>(weffb, padxT, beff, hidbt);
    k_gemm2<<<dim3(NTOT/128, 3), 256, 0, stream>>>(cw2b, hidbt, pa_cb2, xvf, qb16, kvpad);
    k_kvgemm<<<BN*2*PP/128, 256, 0, stream>>>(wkvb, kvpad, kv_b, convb);
    k_pool<<<BN*2*PK*8/256, 256, 0, stream>>>(convb, kbufb, vbufT);
    k_attn3<<<BN*36*2, 256, 0, stream>>>(qb16, kbufb, vbufT, attnp);
    k_out<<<BN*9, 256, 0, stream>>>(attnp, xvf, scales, out_w1, out_b1,
                                    out_w2, out_b2, out);
}

// Round 6
// 132.813 us; speedup vs baseline: 57.1644x; 1.5599x over previous
//
#include <hip/hip_runtime.h>
#include <hip/hip_bf16.h>
#include <math.h>

#define BB 2
#define NVIEW 6
#define BN 12
#define CIN 64
#define HH 48
#define WW 48
#define PP (HH*WW)        // 2304
#define OC 192
#define HPA 192
#define HIDP 64
#define KHW 16
#define PK 256
#define PADW 54
#define PADA (PADW*PADW)  // 2916
#define NTOT (BN*PP)      // 27648
#define K1 1728           // 27 taps * 64 ic
#define KVPW 50
#define KVPA (KVPW*KVPW)  // 2500

typedef __attribute__((ext_vector_type(8))) short bf16x8;
typedef __attribute__((ext_vector_type(4))) float f32x4;

// ---- workspace layout (float elements) ----
#define OFF_WEFFB 0
#define SZ_WEFFB_FL (OC*K1/2)              // 165888
#define OFF_BEFF (OFF_WEFFB + SZ_WEFFB_FL)
#define SZ_BEFF 256
#define OFF_CW2B (OFF_BEFF + SZ_BEFF)
#define SZ_CW2B_FL (OC*OC/2)               // 18432
#define OFF_WKVB (OFF_CW2B + SZ_CW2B_FL)
#define SZ_WKVB_FL (64*576/2)              // 18432
#define OFF_PADXT (OFF_WKVB + SZ_WKVB_FL)
#define SZ_PADXT_FL (BN*PADA*64/2)         // 1119744
#define OFF_QB16 (OFF_PADXT + SZ_PADXT_FL)
#define SZ_QB16_FL (BN*PP*64/2)            // 884736
#define OFF_KB16 (OFF_QB16 + SZ_QB16_FL)
#define SZ_KB16_FL (BN*PK*64/2)            // 98304
#define OFF_VB16T (OFF_KB16 + SZ_KB16_FL)
#define SZ_VB16T_FL (BN*64*PK/2)           // 98304
#define OFF_KVPAD (OFF_VB16T + SZ_VB16T_FL)
#define SZ_KVPAD_FL (BN*2*KVPA*64/2)       // 1920000
#define OFF_CONVB (OFF_KVPAD + SZ_KVPAD_FL)
#define SZ_CONVB_FL (BN*2*PP*64/2)         // 1769472
#define OFF_W1SW (OFF_CONVB + SZ_CONVB_FL)
#define SZ_WSW_FL 2048                     // 4096 bf16
#define OFF_W2SW (OFF_W1SW + SZ_WSW_FL)
#define OFF_ATTNP (OFF_W2SW + SZ_WSW_FL)   // also aliases hidbt (gemm1->gemm2)
#define SZ_ATTNP (BN*PP*HIDP)              // 1769472 per partial, 2 partials
#define OFF_XVB16 (OFF_ATTNP + 2*SZ_ATTNP)
#define SZ_XVB16_FL (BN*PP*64/2)           // 884736 (bf16 [bn][p][d])

__device__ __forceinline__ void load_lds16(const void* g, void* l) {
    __builtin_amdgcn_global_load_lds(
        (const __attribute__((address_space(1))) unsigned int*)g,
        (__attribute__((address_space(3))) unsigned int*)l, 16, 0, 0);
}

__device__ __forceinline__ unsigned short f2bu(float f) {
    __hip_bfloat16 h = __float2bfloat16(f);
    return *(unsigned short*)&h;
}

__device__ __forceinline__ float bu2f(unsigned short h) {
    unsigned int u = ((unsigned int)h) << 16;
    return *(float*)&u;
}

// K1: fold pa_cw1 (192x576) into 3 effective dilated convs -> bf16 [oc][r*576+tap*64+ic]
__global__ void k_fold(const float* __restrict__ cw1, const float* __restrict__ cb1,
                       const float* __restrict__ w1, const float* __restrict__ b1,
                       const float* __restrict__ w2, const float* __restrict__ b2,
                       const float* __restrict__ w3, const float* __restrict__ b3,
                       __hip_bfloat16* __restrict__ weffb, float* __restrict__ beff) {
    int r = blockIdx.x / OC;
    int o = blockIdx.x % OC;
    int t = threadIdx.x;                   // ic*9 + tap
    int ic = t / 9, tap = t % 9;
    const float* w = (r==0) ? w1 : (r==1) ? w2 : w3;
    float acc = 0.f;
    for (int c = 0; c < HPA; ++c)
        acc += cw1[o*(HPA*3) + r*HPA + c] * w[c*(CIN*9) + t];
    weffb[(size_t)o*K1 + r*576 + tap*64 + ic] = __float2bfloat16(acc);
    if (r == 0 && t == 0) {
        float bacc = cb1[o];
        for (int rr = 0; rr < 3; ++rr) {
            const float* bb = (rr==0)?b1:(rr==1)?b2:b3;
            for (int c = 0; c < HPA; ++c)
                bacc += cw1[o*(HPA*3) + rr*HPA + c] * bb[c];
        }
        beff[o] = bacc;
    }
}

// K1b: kv_w [oc][ic][tap] -> bf16 [oc][tap*64+ic]
__global__ void k_wkvb(const float* __restrict__ kvw, __hip_bfloat16* __restrict__ wkvb) {
    int idx = blockIdx.x*256 + threadIdx.x;
    if (idx >= 64*576) return;
    int oc = idx / 576, rest = idx % 576;
    int tap = rest / 64, ic = rest % 64;
    wkvb[idx] = __float2bfloat16(kvw[(oc*64 + ic)*9 + tap]);
}

// K1c: cw2 -> bf16 [oc][ic]
__global__ void k_wcvt(const float* __restrict__ cw2, __hip_bfloat16* __restrict__ cw2b) {
    int idx = blockIdx.x*256 + threadIdx.x;
    if (idx < OC*OC) cw2b[idx] = __float2bfloat16(cw2[idx]);
}

// K1f: out_w1/out_w2 -> pre-swizzled bf16 (LDS-linear order; read with XOR swizzle)
__global__ void k_wout(const float* __restrict__ w1, const float* __restrict__ w2,
                       __hip_bfloat16* __restrict__ w1sw, __hip_bfloat16* __restrict__ w2sw) {
    int idx = blockIdx.x*256 + threadIdx.x;
    if (idx >= 2*4096) return;
    const float* w = (idx < 4096) ? w1 : w2;
    __hip_bfloat16* dst = (idx < 4096) ? w1sw : w2sw;
    int i = idx & 4095;
    int oc = i >> 6, s = (i >> 3) & 7, e = i & 7;
    int k = ((s ^ (oc & 7)) << 3) + e;
    dst[i] = __float2bfloat16(w[oc*64 + k]);
}

// K1d: channels-last padded x, bf16: padxT[bn][spos(54x54)][ic(64)]
__global__ void k_padxT(const float* __restrict__ x, __hip_bfloat16* __restrict__ padxT) {
    int idx = blockIdx.x*256 + threadIdx.x;
    if (idx >= BN*PADA) return;
    int spos = idx % PADA; int bn = idx / PADA;
    int sy = spos / PADW, sx = spos % PADW;
    __hip_bfloat16* dst = padxT + (size_t)idx*64;
    if (sy >= 3 && sy < 51 && sx >= 3 && sx < 51) {
        const float* src = x + (size_t)bn*CIN*PP + (sy-3)*WW + (sx-3);
        #pragma unroll 8
        for (int ic = 0; ic < 64; ++ic) dst[ic] = __float2bfloat16(src[ic*PP]);
    } else {
        #pragma unroll 8
        for (int ic = 0; ic < 64; ++ic) dst[ic] = __float2bfloat16(0.f);
    }
}

// K1e: zero kvpad (halo); interior overwritten by gemm2
__global__ void k_zero(__hip_bfloat16* __restrict__ kvpad) {
    size_t idx = ((size_t)blockIdx.x*256 + threadIdx.x)*8;
    bf16x8 z = (bf16x8){0,0,0,0,0,0,0,0};
    *(bf16x8*)(kvpad + idx) = z;
}

// GEMM1 (implicit dilated conv): hid_bt[n][oc] = relu( weffb[oc][k] * B[k][n] + beff )
__global__ __launch_bounds__(256) void k_gemm1(const __hip_bfloat16* __restrict__ wA,
        const __hip_bfloat16* __restrict__ pxT, const float* __restrict__ beff,
        __hip_bfloat16* __restrict__ hidbt) {
    __shared__ __align__(16) char smem[24576];   // A [64][64] @0, B [128][64] @8192
    int tid = threadIdx.x;
    int wid = tid >> 6, lane = tid & 63;
    int tileN = blockIdx.x * 128, tileM = blockIdx.y * 64;

    size_t gbase[6];
    #pragma unroll
    for (int s2 = 0; s2 < 6; ++s2) {
        int seg = wid*6 + s2;
        if (seg < 8) {
            int row = seg*8 + (lane>>3);
            gbase[s2] = (size_t)(tileM + row)*K1 + (lane&7)*8;
        } else {
            int n = tileN + (seg-8)*8 + (lane>>3);
            int bn = n / PP, p = n % PP;
            int py = p / WW, px = p % WW;
            gbase[s2] = ((size_t)bn*PADA + (py+3)*PADW + (px+3))*64 + (lane&7)*8;
        }
    }
    int wr = wid >> 1, wc = wid & 1;
    int aoff[2], boff[4];
    #pragma unroll
    for (int m = 0; m < 2; ++m)
        aoff[m] = ((wr*32 + m*16 + (lane&15))*64 + (lane>>4)*8)*2;
    #pragma unroll
    for (int nf = 0; nf < 4; ++nf)
        boff[nf] = 8192 + ((wc*64 + nf*16 + (lane&15))*64 + (lane>>4)*8)*2;

    f32x4 acc[2][4];
    #pragma unroll
    for (int m = 0; m < 2; ++m)
        #pragma unroll
        for (int nf = 0; nf < 4; ++nf) acc[m][nf] = (f32x4){0.f,0.f,0.f,0.f};

    for (int kt = 0; kt < 27; ++kt) {
        int r_ = kt / 9, tap = kt - r_*9;
        int dy = tap/3 - 1, dx = tap%3 - 1;
        int doff = (r_+1)*(dy*PADW + dx);
        __syncthreads();
        #pragma unroll
        for (int s2 = 0; s2 < 6; ++s2) {
            int seg = wid*6 + s2;
            const __hip_bfloat16* g = (seg < 8) ? wA + gbase[s2] + kt*64
                                                : pxT + gbase[s2] + (size_t)doff*64;
            load_lds16(g, smem + seg*1024);
        }
        __syncthreads();
        bf16x8 a[2][2], b[4][2];
        #pragma unroll
        for (int m = 0; m < 2; ++m)
            #pragma unroll
            for (int kk = 0; kk < 2; ++kk)
                a[m][kk] = *(const bf16x8*)(smem + aoff[m] + kk*64);
        #pragma unroll
        for (int nf = 0; nf < 4; ++nf)
            #pragma unroll
            for (int kk = 0; kk < 2; ++kk)
                b[nf][kk] = *(const bf16x8*)(smem + boff[nf] + kk*64);
        #pragma unroll
        for (int kk = 0; kk < 2; ++kk)
            #pragma unroll
            for (int m = 0; m < 2; ++m)
                #pragma unroll
                for (int nf = 0; nf < 4; ++nf)
                    acc[m][nf] = __builtin_amdgcn_mfma_f32_16x16x32_bf16(
                        a[m][kk], b[nf][kk], acc[m][nf], 0, 0, 0);
    }
    #pragma unroll
    for (int m = 0; m < 2; ++m) {
        int rbase = tileM + wr*32 + m*16 + (lane>>4)*4;
        float4 bz = *(const float4*)&beff[rbase];
        #pragma unroll
        for (int nf = 0; nf < 4; ++nf) {
            int col = tileN + wc*64 + nf*16 + (lane&15);
            union { ushort4 u; __hip_bfloat16 h[4]; } cv;
            cv.h[0] = __float2bfloat16(fmaxf(acc[m][nf][0] + bz.x, 0.f));
            cv.h[1] = __float2bfloat16(fmaxf(acc[m][nf][1] + bz.y, 0.f));
            cv.h[2] = __float2bfloat16(fmaxf(acc[m][nf][2] + bz.z, 0.f));
            cv.h[3] = __float2bfloat16(fmaxf(acc[m][nf][3] + bz.w, 0.f));
            *(ushort4*)&hidbt[(size_t)col*OC + rbase] = cv.u;
        }
    }
}

// GEMM2: epilogue routes by tileM: q->qb16 [n][d]; k,v->kvpad bf16 channels-last; v also xvb16
__global__ __launch_bounds__(256) void k_gemm2(const __hip_bfloat16* __restrict__ wA,
        const __hip_bfloat16* __restrict__ Bt, const float* __restrict__ cb2,
        __hip_bfloat16* __restrict__ xvb16, __hip_bfloat16* __restrict__ qb16,
        __hip_bfloat16* __restrict__ kvpad) {
    __shared__ __align__(16) char smem[24576];
    int tid = threadIdx.x;
    int wid = tid >> 6, lane = tid & 63;
    int tileN = blockIdx.x * 128, tileM = blockIdx.y * 64;
    size_t gbase[6]; const __hip_bfloat16* gsrc[6];
    #pragma unroll
    for (int s2 = 0; s2 < 6; ++s2) {
        int seg = wid*6 + s2;
        if (seg < 8) {
            int row = seg*8 + (lane>>3);
            gbase[s2] = (size_t)(tileM + row)*OC + (lane&7)*8;
            gsrc[s2] = wA;
        } else {
            int n = tileN + (seg-8)*8 + (lane>>3);
            gbase[s2] = (size_t)n*OC + (lane&7)*8;
            gsrc[s2] = Bt;
        }
    }
    int wr = wid >> 1, wc = wid & 1;
    int aoff[2], boff[4];
    #pragma unroll
    for (int m = 0; m < 2; ++m)
        aoff[m] = ((wr*32 + m*16 + (lane&15))*64 + (lane>>4)*8)*2;
    #pragma unroll
    for (int nf = 0; nf < 4; ++nf)
        boff[nf] = 8192 + ((wc*64 + nf*16 + (lane&15))*64 + (lane>>4)*8)*2;
    f32x4 acc[2][4];
    #pragma unroll
    for (int m = 0; m < 2; ++m)
        #pragma unroll
        for (int nf = 0; nf < 4; ++nf) acc[m][nf] = (f32x4){0.f,0.f,0.f,0.f};

    for (int kt = 0; kt < 3; ++kt) {
        __syncthreads();
        #pragma unroll
        for (int s2 = 0; s2 < 6; ++s2)
            load_lds16(gsrc[s2] + gbase[s2] + kt*64, smem + (wid*6+s2)*1024);
        __syncthreads();
        bf16x8 a[2][2], b[4][2];
        #pragma unroll
        for (int m = 0; m < 2; ++m)
            #pragma unroll
            for (int kk = 0; kk < 2; ++kk)
                a[m][kk] = *(const bf16x8*)(smem + aoff[m] + kk*64);
        #pragma unroll
        for (int nf = 0; nf < 4; ++nf)
            #pragma unroll
            for (int kk = 0; kk < 2; ++kk)
                b[nf][kk] = *(const bf16x8*)(smem + boff[nf] + kk*64);
        #pragma unroll
        for (int kk = 0; kk < 2; ++kk)
            #pragma unroll
            for (int m = 0; m < 2; ++m)
                #pragma unroll
                for (int nf = 0; nf < 4; ++nf)
                    acc[m][nf] = __builtin_amdgcn_mfma_f32_16x16x32_bf16(
                        a[m][kk], b[nf][kk], acc[m][nf], 0, 0, 0);
    }
    #pragma unroll
    for (int m = 0; m < 2; ++m) {
        int rbase = tileM + wr*32 + m*16 + (lane>>4)*4;
        float4 cz = *(const float4*)&cb2[rbase];
        #pragma unroll
        for (int nf = 0; nf < 4; ++nf) {
            int col = tileN + wc*64 + nf*16 + (lane&15);
            int bn = col / PP, p = col % PP;
            float v0 = fmaxf(acc[m][nf][0] + cz.x, 0.f);
            float v1 = fmaxf(acc[m][nf][1] + cz.y, 0.f);
            float v2 = fmaxf(acc[m][nf][2] + cz.z, 0.f);
            float v3 = fmaxf(acc[m][nf][3] + cz.w, 0.f);
            ushort4 bv;
            bv.x = f2bu(v0); bv.y = f2bu(v1); bv.z = f2bu(v2); bv.w = f2bu(v3);
            if (tileM == 0) {
                *(ushort4*)&qb16[(size_t)col*64 + rbase] = bv;
            } else {
                int kv = (tileM == 128) ? 1 : 0;
                int py = p / WW, px = p % WW;
                int d = rbase - tileM;
                *(ushort4*)&kvpad[((size_t)(bn*2+kv)*KVPA + (py+1)*KVPW + px+1)*64 + d] = bv;
                if (kv == 1)
                    *(ushort4*)&xvb16[(size_t)col*64 + d] = bv;
            }
        }
    }
}

// K4a: MFMA conv3x3 64->64 on kvpad -> convb bf16 [bn2][p][64]
__global__ __launch_bounds__(256) void k_kvgemm(const __hip_bfloat16* __restrict__ wA,
        const __hip_bfloat16* __restrict__ kvpad, const float* __restrict__ kvb,
        __hip_bfloat16* __restrict__ convb) {
    __shared__ __align__(16) char smem[24576];
    int tid = threadIdx.x;
    int wid = tid >> 6, lane = tid & 63;
    int tileN = blockIdx.x * 128;
    int bn2 = tileN / PP, p0 = tileN % PP;

    size_t gbase[6];
    #pragma unroll
    for (int s2 = 0; s2 < 6; ++s2) {
        int seg = wid*6 + s2;
        if (seg < 8) {
            int row = seg*8 + (lane>>3);
            gbase[s2] = (size_t)row*576 + (lane&7)*8;
        } else {
            int p = p0 + (seg-8)*8 + (lane>>3);
            int py = p / WW, px = p % WW;
            gbase[s2] = ((size_t)bn2*KVPA + (py+1)*KVPW + px+1)*64 + (lane&7)*8;
        }
    }
    int wr = wid >> 1, wc = wid & 1;
    int aoff[2], boff[4];
    #pragma unroll
    for (int m = 0; m < 2; ++m)
        aoff[m] = ((wr*32 + m*16 + (lane&15))*64 + (lane>>4)*8)*2;
    #pragma unroll
    for (int nf = 0; nf < 4; ++nf)
        boff[nf] = 8192 + ((wc*64 + nf*16 + (lane&15))*64 + (lane>>4)*8)*2;

    f32x4 acc[2][4];
    #pragma unroll
    for (int m = 0; m < 2; ++m)
        #pragma unroll
        for (int nf = 0; nf < 4; ++nf) acc[m][nf] = (f32x4){0.f,0.f,0.f,0.f};

    for (int kt = 0; kt < 9; ++kt) {
        int dy = kt/3 - 1, dx = kt%3 - 1;
        int doff = dy*KVPW + dx;
        __syncthreads();
        #pragma unroll
        for (int s2 = 0; s2 < 6; ++s2) {
            int seg = wid*6 + s2;
            const __hip_bfloat16* g = (seg < 8) ? wA + gbase[s2] + kt*64
                                                : kvpad + gbase[s2] + (size_t)doff*64;
            load_lds16(g, smem + seg*1024);
        }
        __syncthreads();
        bf16x8 a[2][2], b[4][2];
        #pragma unroll
        for (int m = 0; m < 2; ++m)
            #pragma unroll
            for (int kk = 0; kk < 2; ++kk)
                a[m][kk] = *(const bf16x8*)(smem + aoff[m] + kk*64);
        #pragma unroll
        for (int nf = 0; nf < 4; ++nf)
            #pragma unroll
            for (int kk = 0; kk < 2; ++kk)
                b[nf][kk] = *(const bf16x8*)(smem + boff[nf] + kk*64);
        #pragma unroll
        for (int kk = 0; kk < 2; ++kk)
            #pragma unroll
            for (int m = 0; m < 2; ++m)
                #pragma unroll
                for (int nf = 0; nf < 4; ++nf)
                    acc[m][nf] = __builtin_amdgcn_mfma_f32_16x16x32_bf16(
                        a[m][kk], b[nf][kk], acc[m][nf], 0, 0, 0);
    }
    #pragma unroll
    for (int m = 0; m < 2; ++m) {
        int rbase = wr*32 + m*16 + (lane>>4)*4;
        float4 bz = *(const float4*)&kvb[rbase];
        #pragma unroll
        for (int nf = 0; nf < 4; ++nf) {
            int col = p0 + wc*64 + nf*16 + (lane&15);
            ushort4 cv;
            cv.x = f2bu(fmaxf(acc[m][nf][0] + bz.x, 0.f));
            cv.y = f2bu(fmaxf(acc[m][nf][1] + bz.y, 0.f));
            cv.z = f2bu(fmaxf(acc[m][nf][2] + bz.z, 0.f));
            cv.w = f2bu(fmaxf(acc[m][nf][3] + bz.w, 0.f));
            *(ushort4*)&convb[((size_t)bn2*PP + col)*64 + rbase] = cv;
        }
    }
}

// K4b: 3x3 avgpool on convb -> kbufb bf16 [bn][k][d], vbufT bf16 [bn][d][k]
__global__ __launch_bounds__(256) void k_pool(const __hip_bfloat16* __restrict__ convb,
        __hip_bfloat16* __restrict__ kbufb, __hip_bfloat16* __restrict__ vbufT) {
    int idx = blockIdx.x*256 + threadIdx.x;
    int dg = idx % 8; idx /= 8;
    int pp = idx % PK; idx /= PK;
    int bn2 = idx;                       // bn*2+kv
    int kv = bn2 & 1, bn = bn2 >> 1;
    int qy = pp / KHW, qx = pp % KHW;
    float s[8] = {0,0,0,0,0,0,0,0};
    const __hip_bfloat16* base = convb + (size_t)bn2*PP*64 + dg*8;
    #pragma unroll
    for (int sy = 0; sy < 3; ++sy)
        #pragma unroll
        for (int sx = 0; sx < 3; ++sx) {
            union { bf16x8 v; unsigned short h[8]; } c;
            c.v = *(const bf16x8*)(base + ((size_t)(qy*3+sy)*WW + qx*3+sx)*64);
            #pragma unroll
            for (int j = 0; j < 8; ++j) s[j] += bu2f(c.h[j]);
        }
    if (kv == 0) {
        union { ushort4 u[2]; unsigned short h[8]; } cv;
        #pragma unroll
        for (int j = 0; j < 8; ++j) cv.h[j] = f2bu(s[j] * (1.f/9.f));
        ushort4* dst = (ushort4*)(kbufb + ((size_t)bn*PK + pp)*64 + dg*8);
        dst[0] = cv.u[0]; dst[1] = cv.u[1];
    } else {
        #pragma unroll
        for (int j = 0; j < 8; ++j)
            vbufT[((size_t)bn*64 + dg*8 + j)*PK + pp] = __float2bfloat16(s[j]*(1.f/81.f));
    }
}

// K5: MFMA leave-one-out sigmoid attention.
__global__ __launch_bounds__(256) void k_attn3(const __hip_bfloat16* __restrict__ qb16,
        const __hip_bfloat16* __restrict__ kbufb, const __hip_bfloat16* __restrict__ vbufT,
        float* __restrict__ attnp) {
    __shared__ __align__(16) char smem[32768];
    char* Qs = smem;
    char* Ks = smem + 8192;
    char* Vs = smem + 16384;
    char* Ps = smem + 24576;
    int tid = threadIdx.x;
    int wid = tid >> 6, lane = tid & 63;
    int bid = blockIdx.x;
    int ks = bid & 1; bid >>= 1;
    int qt = bid % 36; int bn = bid / 36;
    int b = bn / NVIEW, n = bn % NVIEW;
    int p0 = qt*64;

    {
        const char* gq = (const char*)(qb16 + ((size_t)bn*PP + p0)*64);
        #pragma unroll
        for (int i = 0; i < 2; ++i) {
            int s = wid*2 + i;
            int lin = s*1024 + lane*16;
            int r = lin >> 7, c = (lin >> 4) & 7;
            int gof = (r<<7) + ((c ^ (r&7)) << 4);
            load_lds16(gq + gof, Qs + s*1024);
        }
    }
    int arow = wid*16 + (lane&15);
    int brow = lane&15;
    int gcol = lane>>4;
    int vrow = tid >> 2;
    int vc2 = (tid & 3) * 2;

    f32x4 oacc[4];
    #pragma unroll
    for (int i = 0; i < 4; ++i) oacc[i] = (f32x4){0,0,0,0};

    for (int mi = 0; mi < NVIEW-1; ++mi) {
        int m = mi + (mi >= n ? 1 : 0);
        int bnk = b*NVIEW + m;
        const char* gk = (const char*)(kbufb + (size_t)bnk*PK*64);
        const __hip_bfloat16* gv = vbufT + (size_t)bnk*64*PK;
        for (int kc = ks*2; kc < ks*2+2; ++kc) {
            __syncthreads();
            #pragma unroll
            for (int i = 0; i < 2; ++i) {
                int s = wid*2 + i;
                int lin = s*1024 + lane*16;
                int r = lin >> 7, c = (lin >> 4) & 7;
                int gof = (r<<7) + ((c ^ (r&7)) << 4);
                load_lds16(gk + (size_t)kc*8192 + gof, Ks + s*1024);
            }
            {
                const __hip_bfloat16* src = gv + vrow*PK + kc*64 + vc2*8;
                bf16x8 v0 = *(const bf16x8*)src;
                bf16x8 v1 = *(const bf16x8*)(src+8);
                *(bf16x8*)(Vs + vrow*128 + ((vc2 ^ (vrow&7))<<4)) = v0;
                *(bf16x8*)(Vs + vrow*128 + (((vc2+1) ^ (vrow&7))<<4)) = v1;
            }
            __syncthreads();
            f32x4 sacc[4];
            #pragma unroll
            for (int i = 0; i < 4; ++i) sacc[i] = (f32x4){0,0,0,0};
            #pragma unroll
            for (int kk = 0; kk < 2; ++kk) {
                int g = kk*4 + gcol;
                bf16x8 af = *(const bf16x8*)(Ks + arow*128 + ((g ^ (arow&7))<<4));
                #pragma unroll
                for (int nf = 0; nf < 4; ++nf) {
                    int q = nf*16 + brow;
                    bf16x8 bq = *(const bf16x8*)(Qs + q*128 + ((g ^ (q&7))<<4));
                    sacc[nf] = __builtin_amdgcn_mfma_f32_16x16x32_bf16(af, bq, sacc[nf], 0,0,0);
                }
            }
            {
                int kbase = wid*16 + gcol*4;
                #pragma unroll
                for (int nf = 0; nf < 4; ++nf) {
                    int q = nf*16 + brow;
                    ushort4 pu;
                    float e0 = __expf(-sacc[nf][0]*0.125f);
                    float e1 = __expf(-sacc[nf][1]*0.125f);
                    float e2 = __expf(-sacc[nf][2]*0.125f);
                    float e3 = __expf(-sacc[nf][3]*0.125f);
                    pu.x = f2bu(__builtin_amdgcn_rcpf(1.f+e0));
                    pu.y = f2bu(__builtin_amdgcn_rcpf(1.f+e1));
                    pu.z = f2bu(__builtin_amdgcn_rcpf(1.f+e2));
                    pu.w = f2bu(__builtin_amdgcn_rcpf(1.f+e3));
                    *(ushort4*)(Ps + q*128 + (((kbase>>3) ^ (q&7))<<4) + (kbase&7)*2) = pu;
                }
            }
            __syncthreads();
            #pragma unroll
            for (int kk = 0; kk < 2; ++kk) {
                int g = kk*4 + gcol;
                int qr = wid*16 + brow;
                bf16x8 pf = *(const bf16x8*)(Ps + qr*128 + ((g ^ (qr&7))<<4));
                #pragma unroll
                for (int nf = 0; nf < 4; ++nf) {
                    int d = nf*16 + brow;
                    bf16x8 vf = *(const bf16x8*)(Vs + d*128 + ((g ^ (d&7))<<4));
                    oacc[nf] = __builtin_amdgcn_mfma_f32_16x16x32_bf16(pf, vf, oacc[nf], 0,0,0);
                }
            }
        }
    }
    float* ab = attnp + (size_t)ks*SZ_ATTNP + ((size_t)bn*PP + p0)*64;
    #pragma unroll
    for (int nf = 0; nf < 4; ++nf) {
        #pragma unroll
        for (int r = 0; r < 4; ++r) {
            int q = wid*16 + gcol*4 + r;
            int d = nf*16 + brow;
            ab[(size_t)q*64 + d] = oacc[nf][r];
        }
    }
}

// K6: MFMA epilogue: out = relu(W2 relu(W1 relu(attn0+attn1 + sc*xv) + b1) + b2)
// block: 128 pixels. LDS: W1s@0 8K, W2s@8K, Rs@16K 16K, Ts@32K 16K (all XOR-swizzled rows)
__global__ __launch_bounds__(256) void k_out2(const float* __restrict__ attnp,
        const __hip_bfloat16* __restrict__ xvb16, const float* __restrict__ scales,
        const __hip_bfloat16* __restrict__ w1sw, const __hip_bfloat16* __restrict__ w2sw,
        const float* __restrict__ b1, const float* __restrict__ b2,
        float* __restrict__ out) {
    __shared__ __align__(16) char smem[49152];
    char* W1s = smem;
    char* W2s = smem + 8192;
    char* Rs  = smem + 16384;
    char* Ts  = smem + 32768;
    int tid = threadIdx.x;
    int wid = tid >> 6, lane = tid & 63;
    int pix0 = blockIdx.x * 128;
    int bn = pix0 / PP;
    int pb = pix0 - bn*PP;
    float sc = scales[bn % NVIEW];

    // stage W1,W2 (pre-swizzled, linear LDS): 16 segs of 1KB
    #pragma unroll
    for (int i = 0; i < 4; ++i) {
        int seg = wid*4 + i;
        const char* src = (seg < 8) ? (const char*)w1sw + seg*1024
                                    : (const char*)w2sw + (seg-8)*1024;
        load_lds16(src + lane*16, smem + seg*1024);
    }
    // Rs = relu(a0+a1+sc*xv) bf16, swizzled rows
    {
        int p = tid >> 1, d0 = (tid & 1) * 32;
        int P = pix0 + p;
        const float* a0 = attnp + (size_t)P*64 + d0;
        const float* a1 = a0 + SZ_ATTNP;
        const __hip_bfloat16* xv = xvb16 + (size_t)P*64 + d0;
        #pragma unroll
        for (int j = 0; j < 4; ++j) {
            float4 u0 = *(const float4*)(a0 + j*8);
            float4 u1 = *(const float4*)(a0 + j*8 + 4);
            float4 v0 = *(const float4*)(a1 + j*8);
            float4 v1 = *(const float4*)(a1 + j*8 + 4);
            union { bf16x8 v; unsigned short h[8]; } xu;
            xu.v = *(const bf16x8*)(xv + j*8);
            union { bf16x8 v; unsigned short h[8]; } rv;
            rv.h[0] = f2bu(fmaxf(u0.x + v0.x + sc*bu2f(xu.h[0]), 0.f));
            rv.h[1] = f2bu(fmaxf(u0.y + v0.y + sc*bu2f(xu.h[1]), 0.f));
            rv.h[2] = f2bu(fmaxf(u0.z + v0.z + sc*bu2f(xu.h[2]), 0.f));
            rv.h[3] = f2bu(fmaxf(u0.w + v0.w + sc*bu2f(xu.h[3]), 0.f));
            rv.h[4] = f2bu(fmaxf(u1.x + v1.x + sc*bu2f(xu.h[4]), 0.f));
            rv.h[5] = f2bu(fmaxf(u1.y + v1.y + sc*bu2f(xu.h[5]), 0.f));
            rv.h[6] = f2bu(fmaxf(u1.z + v1.z + sc*bu2f(xu.h[6]), 0.f));
            rv.h[7] = f2bu(fmaxf(u1.w + v1.w + sc*bu2f(xu.h[7]), 0.f));
            int g = (d0 >> 3) + j;
            *(bf16x8*)(Rs + p*128 + ((g ^ (p&7)) << 4)) = rv.v;
        }
    }
    __syncthreads();

    int wr = wid >> 1, wc = wid & 1;
    int rrow = lane & 15, gcol = lane >> 4;
    // GEMM1: t[oc][px] = relu(W1 . Rs + b1)
    f32x4 acc1[2][4];
    #pragma unroll
    for (int m = 0; m < 2; ++m)
        #pragma unroll
        for (int nf = 0; nf < 4; ++nf) acc1[m][nf] = (f32x4){0,0,0,0};
    #pragma unroll
    for (int kk = 0; kk < 2; ++kk) {
        int g = kk*4 + gcol;
        #pragma unroll
        for (int m = 0; m < 2; ++m) {
            int oc = wr*32 + m*16 + rrow;
            bf16x8 af = *(const bf16x8*)(W1s + oc*128 + ((g ^ (oc&7)) << 4));
            #pragma unroll
            for (int nf = 0; nf < 4; ++nf) {
                int px = wc*64 + nf*16 + rrow;
                bf16x8 bf = *(const bf16x8*)(Rs + px*128 + ((g ^ (px&7)) << 4));
                acc1[m][nf] = __builtin_amdgcn_mfma_f32_16x16x32_bf16(af, bf, acc1[m][nf], 0,0,0);
            }
        }
    }
    #pragma unroll
    for (int m = 0; m < 2; ++m) {
        int oc0 = wr*32 + m*16 + gcol*4;
        float4 bz = *(const float4*)&b1[oc0];
        #pragma unroll
        for (int nf = 0; nf < 4; ++nf) {
            int px = wc*64 + nf*16 + rrow;
            ushort4 tv;
            tv.x = f2bu(fmaxf(acc1[m][nf][0] + bz.x, 0.f));
            tv.y = f2bu(fmaxf(acc1[m][nf][1] + bz.y, 0.f));
            tv.z = f2bu(fmaxf(acc1[m][nf][2] + bz.z, 0.f));
            tv.w = f2bu(fmaxf(acc1[m][nf][3] + bz.w, 0.f));
            *(ushort4*)(Ts + px*128 + (((oc0>>3) ^ (px&7)) << 4) + (oc0&7)*2) = tv;
        }
    }
    __syncthreads();
    // GEMM2: out[oc][px] = relu(W2 . Ts + b2)
    f32x4 acc2[2][4];
    #pragma unroll
    for (int m = 0; m < 2; ++m)
        #pragma unroll
        for (int nf = 0; nf < 4; ++nf) acc2[m][nf] = (f32x4){0,0,0,0};
    #pragma unroll
    for (int kk = 0; kk < 2; ++kk) {
        int g = kk*4 + gcol;
        #pragma unroll
        for (int m = 0; m < 2; ++m) {
            int oc = wr*32 + m*16 + rrow;
            bf16x8 af = *(const bf16x8*)(W2s + oc*128 + ((g ^ (oc&7)) << 4));
            #pragma unroll
            for (int nf = 0; nf < 4; ++nf) {
                int px = wc*64 + nf*16 + rrow;
                bf16x8 bf = *(const bf16x8*)(Ts + px*128 + ((g ^ (px&7)) << 4));
                acc2[m][nf] = __builtin_amdgcn_mfma_f32_16x16x32_bf16(af, bf, acc2[m][nf], 0,0,0);
            }
        }
    }
    #pragma unroll
    for (int m = 0; m < 2; ++m) {
        int oc0 = wr*32 + m*16 + gcol*4;
        float4 bz = *(const float4*)&b2[oc0];
        #pragma unroll
        for (int nf = 0; nf < 4; ++nf) {
            int px = wc*64 + nf*16 + rrow;
            float* dst = out + ((size_t)bn*64 + oc0)*PP + pb + px;
            dst[0*PP] = fmaxf(acc2[m][nf][0] + bz.x, 0.f);
            dst[1*PP] = fmaxf(acc2[m][nf][1] + bz.y, 0.f);
            dst[2*PP] = fmaxf(acc2[m][nf][2] + bz.z, 0.f);
            dst[3*PP] = fmaxf(acc2[m][nf][3] + bz.w, 0.f);
        }
    }
}

extern "C" void kernel_launch(void* const* d_in, const int* in_sizes, int n_in,
                              void* d_out, int out_size, void* d_ws, size_t ws_size,
                              hipStream_t stream) {
    (void)in_sizes; (void)n_in; (void)out_size; (void)ws_size;
    const float* x      = (const float*)d_in[0];
    const float* pa_w1  = (const float*)d_in[1];
    const float* pa_b1  = (const float*)d_in[2];
    const float* pa_w2  = (const float*)d_in[3];
    const float* pa_b2  = (const float*)d_in[4];
    const float* pa_w3  = (const float*)d_in[5];
    const float* pa_b3  = (const float*)d_in[6];
    const float* pa_cw1 = (const float*)d_in[7];
    const float* pa_cb1 = (const float*)d_in[8];
    const float* pa_cw2 = (const float*)d_in[9];
    const float* pa_cb2 = (const float*)d_in[10];
    const float* kv_w   = (const float*)d_in[11];
    const float* kv_b   = (const float*)d_in[12];
    const float* out_w1 = (const float*)d_in[13];
    const float* out_b1 = (const float*)d_in[14];
    const float* out_w2 = (const float*)d_in[15];
    const float* out_b2 = (const float*)d_in[16];
    const float* scales = (const float*)d_in[17];
    float* out = (float*)d_out;
    float* ws  = (float*)d_ws;

    __hip_bfloat16* weffb = (__hip_bfloat16*)(ws + OFF_WEFFB);
    float* beff = ws + OFF_BEFF;
    __hip_bfloat16* cw2b  = (__hip_bfloat16*)(ws + OFF_CW2B);
    __hip_bfloat16* wkvb  = (__hip_bfloat16*)(ws + OFF_WKVB);
    __hip_bfloat16* padxT = (__hip_bfloat16*)(ws + OFF_PADXT);
    __hip_bfloat16* qb16  = (__hip_bfloat16*)(ws + OFF_QB16);
    __hip_bfloat16* kbufb = (__hip_bfloat16*)(ws + OFF_KB16);
    __hip_bfloat16* vbufT = (__hip_bfloat16*)(ws + OFF_VB16T);
    __hip_bfloat16* kvpad = (__hip_bfloat16*)(ws + OFF_KVPAD);
    __hip_bfloat16* convb = (__hip_bfloat16*)(ws + OFF_CONVB);
    __hip_bfloat16* w1sw  = (__hip_bfloat16*)(ws + OFF_W1SW);
    __hip_bfloat16* w2sw  = (__hip_bfloat16*)(ws + OFF_W2SW);
    __hip_bfloat16* hidbt = (__hip_bfloat16*)(ws + OFF_ATTNP);  // alias (pre-attn)
    float* attnp = ws + OFF_ATTNP;
    __hip_bfloat16* xvb16 = (__hip_bfloat16*)(ws + OFF_XVB16);

    k_fold<<<3*OC, CIN*9, 0, stream>>>(pa_cw1, pa_cb1, pa_w1, pa_b1,
                                       pa_w2, pa_b2, pa_w3, pa_b3, weffb, beff);
    k_wkvb<<<(64*576+255)/256, 256, 0, stream>>>(kv_w, wkvb);
    k_wcvt<<<(OC*OC+255)/256, 256, 0, stream>>>(pa_cw2, cw2b);
    k_wout<<<(2*4096+255)/256, 256, 0, stream>>>(out_w1, out_w2, w1sw, w2sw);
    k_padxT<<<(BN*PADA+255)/256, 256, 0, stream>>>(x, padxT);
    k_zero<<<(BN*2*KVPA*64/8)/256, 256, 0, stream>>>(kvpad);
    k_gemm1<<<dim3(NTOT/128, 3), 256, 0, stream>>>(weffb, padxT, beff, hidbt);
    k_gemm2<<<dim3(NTOT/128, 3), 256, 0, stream>>>(cw2b, hidbt, pa_cb2, xvb16, qb16, kvpad);
    k_kvgemm<<<BN*2*PP/128, 256, 0, stream>>>(wkvb, kvpad, kv_b, convb);
    k_pool<<<BN*2*PK*8/256, 256, 0, stream>>>(convb, kbufb, vbufT);
    k_attn3<<<BN*36*2, 256, 0, stream>>>(qb16, kbufb, vbufT, attnp);
    k_out2<<<NTOT/128, 256, 0, stream>>>(attnp, xvb16, scales, w1sw, w2sw,
                                         out_b1, out_b2, out);
}

// Round 7
// 122.208 us; speedup vs baseline: 62.1250x; 1.0868x over previous
//
#include <hip/hip_runtime.h>
#include <hip/hip_bf16.h>
#include <math.h>

#define BB 2
#define NVIEW 6
#define BN 12
#define CIN 64
#define HH 48
#define WW 48
#define PP (HH*WW)        // 2304
#define OC 192
#define HPA 192
#define HIDP 64
#define KHW 16
#define PK 256
#define PADW 54
#define PADA (PADW*PADW)  // 2916
#define NTOT (BN*PP)      // 27648
#define K1 1728           // 27 taps * 64 ic
#define KVPW 50
#define KVPA (KVPW*KVPW)  // 2500

typedef __attribute__((ext_vector_type(8))) short bf16x8;
typedef __attribute__((ext_vector_type(4))) float f32x4;

// ---- workspace layout (float elements) ----
#define OFF_WEFFB 0
#define SZ_WEFFB_FL (OC*K1/2)              // 165888
#define OFF_BEFF (OFF_WEFFB + SZ_WEFFB_FL)
#define SZ_BEFF 256
#define OFF_CW2B (OFF_BEFF + SZ_BEFF)
#define SZ_CW2B_FL (OC*OC/2)               // 18432
#define OFF_WKVB (OFF_CW2B + SZ_CW2B_FL)
#define SZ_WKVB_FL (64*576/2)              // 18432
#define OFF_PADXT (OFF_WKVB + SZ_WKVB_FL)
#define SZ_PADXT_FL (BN*PADA*64/2)         // 1119744
#define OFF_QB16 (OFF_PADXT + SZ_PADXT_FL)
#define SZ_QB16_FL (BN*PP*64/2)            // 884736
#define OFF_KB16 (OFF_QB16 + SZ_QB16_FL)
#define SZ_KB16_FL (BN*PK*64/2)            // 98304
#define OFF_VB16T (OFF_KB16 + SZ_KB16_FL)
#define SZ_VB16T_FL (BN*64*PK/2)           // 98304
#define OFF_KVPAD (OFF_VB16T + SZ_VB16T_FL)
#define SZ_KVPAD_FL (BN*2*KVPA*64/2)       // 1920000
#define OFF_CONVB (OFF_KVPAD + SZ_KVPAD_FL)
#define SZ_CONVB_FL (BN*2*PP*64/2)         // 1769472
#define OFF_W1SW (OFF_CONVB + SZ_CONVB_FL)
#define SZ_WSW_FL 2048                     // 4096 bf16
#define OFF_W2SW (OFF_W1SW + SZ_WSW_FL)
#define OFF_ATTNP (OFF_W2SW + SZ_WSW_FL)   // also aliases hidbt (gemm1->gemm2)
#define SZ_ATTNP (BN*PP*HIDP)              // 1769472 per partial, 2 partials
#define OFF_XVB16 (OFF_ATTNP + 2*SZ_ATTNP)
#define SZ_XVB16_FL (BN*PP*64/2)           // 884736 (bf16 [bn][p][d])

__device__ __forceinline__ void load_lds16(const void* g, void* l) {
    __builtin_amdgcn_global_load_lds(
        (const __attribute__((address_space(1))) unsigned int*)g,
        (__attribute__((address_space(3))) unsigned int*)l, 16, 0, 0);
}

__device__ __forceinline__ unsigned short f2bu(float f) {
    __hip_bfloat16 h = __float2bfloat16(f);
    return *(unsigned short*)&h;
}

__device__ __forceinline__ float bu2f(unsigned short h) {
    unsigned int u = ((unsigned int)h) << 16;
    return *(float*)&u;
}

// K1: fold pa_cw1 (192x576) into 3 effective dilated convs -> bf16 [oc][r*576+tap*64+ic]
__global__ void k_fold(const float* __restrict__ cw1, const float* __restrict__ cb1,
                       const float* __restrict__ w1, const float* __restrict__ b1,
                       const float* __restrict__ w2, const float* __restrict__ b2,
                       const float* __restrict__ w3, const float* __restrict__ b3,
                       __hip_bfloat16* __restrict__ weffb, float* __restrict__ beff) {
    int r = blockIdx.x / OC;
    int o = blockIdx.x % OC;
    int t = threadIdx.x;                   // ic*9 + tap
    int ic = t / 9, tap = t % 9;
    const float* w = (r==0) ? w1 : (r==1) ? w2 : w3;
    float acc = 0.f;
    for (int c = 0; c < HPA; ++c)
        acc += cw1[o*(HPA*3) + r*HPA + c] * w[c*(CIN*9) + t];
    weffb[(size_t)o*K1 + r*576 + tap*64 + ic] = __float2bfloat16(acc);
    if (r == 0 && t == 0) {
        float bacc = cb1[o];
        for (int rr = 0; rr < 3; ++rr) {
            const float* bb = (rr==0)?b1:(rr==1)?b2:b3;
            for (int c = 0; c < HPA; ++c)
                bacc += cw1[o*(HPA*3) + rr*HPA + c] * bb[c];
        }
        beff[o] = bacc;
    }
}

// K1b: kv_w [oc][ic][tap] -> bf16 [oc][tap*64+ic]
__global__ void k_wkvb(const float* __restrict__ kvw, __hip_bfloat16* __restrict__ wkvb) {
    int idx = blockIdx.x*256 + threadIdx.x;
    if (idx >= 64*576) return;
    int oc = idx / 576, rest = idx % 576;
    int tap = rest / 64, ic = rest % 64;
    wkvb[idx] = __float2bfloat16(kvw[(oc*64 + ic)*9 + tap]);
}

// K1c: cw2 -> bf16 [oc][ic]
__global__ void k_wcvt(const float* __restrict__ cw2, __hip_bfloat16* __restrict__ cw2b) {
    int idx = blockIdx.x*256 + threadIdx.x;
    if (idx < OC*OC) cw2b[idx] = __float2bfloat16(cw2[idx]);
}

// K1f: out_w1/out_w2 -> pre-swizzled bf16 (LDS-linear order; read with XOR swizzle)
__global__ void k_wout(const float* __restrict__ w1, const float* __restrict__ w2,
                       __hip_bfloat16* __restrict__ w1sw, __hip_bfloat16* __restrict__ w2sw) {
    int idx = blockIdx.x*256 + threadIdx.x;
    if (idx >= 2*4096) return;
    const float* w = (idx < 4096) ? w1 : w2;
    __hip_bfloat16* dst = (idx < 4096) ? w1sw : w2sw;
    int i = idx & 4095;
    int oc = i >> 6, s = (i >> 3) & 7, e = i & 7;
    int k = ((s ^ (oc & 7)) << 3) + e;
    dst[i] = __float2bfloat16(w[oc*64 + k]);
}

// K1d: channels-last padded x, bf16: padxT[bn][spos(54x54)][ic(64)]
__global__ void k_padxT(const float* __restrict__ x, __hip_bfloat16* __restrict__ padxT) {
    int idx = blockIdx.x*256 + threadIdx.x;
    if (idx >= BN*PADA) return;
    int spos = idx % PADA; int bn = idx / PADA;
    int sy = spos / PADW, sx = spos % PADW;
    __hip_bfloat16* dst = padxT + (size_t)idx*64;
    if (sy >= 3 && sy < 51 && sx >= 3 && sx < 51) {
        const float* src = x + (size_t)bn*CIN*PP + (sy-3)*WW + (sx-3);
        #pragma unroll 8
        for (int ic = 0; ic < 64; ++ic) dst[ic] = __float2bfloat16(src[ic*PP]);
    } else {
        #pragma unroll 8
        for (int ic = 0; ic < 64; ++ic) dst[ic] = __float2bfloat16(0.f);
    }
}

// K1e: zero kvpad (halo); interior overwritten by gemm2
__global__ void k_zero(__hip_bfloat16* __restrict__ kvpad) {
    size_t idx = ((size_t)blockIdx.x*256 + threadIdx.x)*8;
    bf16x8 z = (bf16x8){0,0,0,0,0,0,0,0};
    *(bf16x8*)(kvpad + idx) = z;
}

// GEMM1 (implicit dilated conv): hid_bt[n][oc] = relu( weffb[oc][k] * B[k][n] + beff )
// LDS rows XOR-granule swizzled: stage with per-lane source granule (lane&7)^(lane>>3),
// frag-read granule g^(row&7).  [T2 / G21 both-sides swizzle]
__global__ __launch_bounds__(256) void k_gemm1(const __hip_bfloat16* __restrict__ wA,
        const __hip_bfloat16* __restrict__ pxT, const float* __restrict__ beff,
        __hip_bfloat16* __restrict__ hidbt) {
    __shared__ __align__(16) char smem[24576];   // A [64][64] @0, B [128][64] @8192
    int tid = threadIdx.x;
    int wid = tid >> 6, lane = tid & 63;
    int tileN = blockIdx.x * 128, tileM = blockIdx.y * 64;
    int sgr = ((lane&7) ^ (lane>>3)) * 8;        // swizzled source granule (elements)

    size_t gbase[6];
    #pragma unroll
    for (int s2 = 0; s2 < 6; ++s2) {
        int seg = wid*6 + s2;
        if (seg < 8) {
            int row = seg*8 + (lane>>3);
            gbase[s2] = (size_t)(tileM + row)*K1 + sgr;
        } else {
            int n = tileN + (seg-8)*8 + (lane>>3);
            int bn = n / PP, p = n % PP;
            int py = p / WW, px = p % WW;
            gbase[s2] = ((size_t)bn*PADA + (py+3)*PADW + (px+3))*64 + sgr;
        }
    }
    int wr = wid >> 1, wc = wid & 1;
    int l7 = lane & 7, lh = lane >> 4;
    int arowb[2], browb[4];
    #pragma unroll
    for (int m = 0; m < 2; ++m)
        arowb[m] = (wr*32 + m*16 + (lane&15))*128;
    #pragma unroll
    for (int nf = 0; nf < 4; ++nf)
        browb[nf] = 8192 + (wc*64 + nf*16 + (lane&15))*128;

    f32x4 acc[2][4];
    #pragma unroll
    for (int m = 0; m < 2; ++m)
        #pragma unroll
        for (int nf = 0; nf < 4; ++nf) acc[m][nf] = (f32x4){0.f,0.f,0.f,0.f};

    for (int kt = 0; kt < 27; ++kt) {
        int r_ = kt / 9, tap = kt - r_*9;
        int dy = tap/3 - 1, dx = tap%3 - 1;
        int doff = (r_+1)*(dy*PADW + dx);
        __syncthreads();
        #pragma unroll
        for (int s2 = 0; s2 < 6; ++s2) {
            int seg = wid*6 + s2;
            const __hip_bfloat16* g = (seg < 8) ? wA + gbase[s2] + kt*64
                                                : pxT + gbase[s2] + (size_t)doff*64;
            load_lds16(g, smem + seg*1024);
        }
        __syncthreads();
        bf16x8 a[2][2], b[4][2];
        #pragma unroll
        for (int kk = 0; kk < 2; ++kk) {
            int gof = ((kk*4 + lh) ^ l7) << 4;
            #pragma unroll
            for (int m = 0; m < 2; ++m)
                a[m][kk] = *(const bf16x8*)(smem + arowb[m] + gof);
            #pragma unroll
            for (int nf = 0; nf < 4; ++nf)
                b[nf][kk] = *(const bf16x8*)(smem + browb[nf] + gof);
        }
        #pragma unroll
        for (int kk = 0; kk < 2; ++kk)
            #pragma unroll
            for (int m = 0; m < 2; ++m)
                #pragma unroll
                for (int nf = 0; nf < 4; ++nf)
                    acc[m][nf] = __builtin_amdgcn_mfma_f32_16x16x32_bf16(
                        a[m][kk], b[nf][kk], acc[m][nf], 0, 0, 0);
    }
    #pragma unroll
    for (int m = 0; m < 2; ++m) {
        int rbase = tileM + wr*32 + m*16 + (lane>>4)*4;
        float4 bz = *(const float4*)&beff[rbase];
        #pragma unroll
        for (int nf = 0; nf < 4; ++nf) {
            int col = tileN + wc*64 + nf*16 + (lane&15);
            union { ushort4 u; __hip_bfloat16 h[4]; } cv;
            cv.h[0] = __float2bfloat16(fmaxf(acc[m][nf][0] + bz.x, 0.f));
            cv.h[1] = __float2bfloat16(fmaxf(acc[m][nf][1] + bz.y, 0.f));
            cv.h[2] = __float2bfloat16(fmaxf(acc[m][nf][2] + bz.z, 0.f));
            cv.h[3] = __float2bfloat16(fmaxf(acc[m][nf][3] + bz.w, 0.f));
            *(ushort4*)&hidbt[(size_t)col*OC + rbase] = cv.u;
        }
    }
}

// GEMM2: epilogue routes by tileM: q->qb16 [n][d]; k,v->kvpad bf16 channels-last; v also xvb16
__global__ __launch_bounds__(256) void k_gemm2(const __hip_bfloat16* __restrict__ wA,
        const __hip_bfloat16* __restrict__ Bt, const float* __restrict__ cb2,
        __hip_bfloat16* __restrict__ xvb16, __hip_bfloat16* __restrict__ qb16,
        __hip_bfloat16* __restrict__ kvpad) {
    __shared__ __align__(16) char smem[24576];
    int tid = threadIdx.x;
    int wid = tid >> 6, lane = tid & 63;
    int tileN = blockIdx.x * 128, tileM = blockIdx.y * 64;
    int sgr = ((lane&7) ^ (lane>>3)) * 8;
    size_t gbase[6]; const __hip_bfloat16* gsrc[6];
    #pragma unroll
    for (int s2 = 0; s2 < 6; ++s2) {
        int seg = wid*6 + s2;
        if (seg < 8) {
            int row = seg*8 + (lane>>3);
            gbase[s2] = (size_t)(tileM + row)*OC + sgr;
            gsrc[s2] = wA;
        } else {
            int n = tileN + (seg-8)*8 + (lane>>3);
            gbase[s2] = (size_t)n*OC + sgr;
            gsrc[s2] = Bt;
        }
    }
    int wr = wid >> 1, wc = wid & 1;
    int l7 = lane & 7, lh = lane >> 4;
    int arowb[2], browb[4];
    #pragma unroll
    for (int m = 0; m < 2; ++m)
        arowb[m] = (wr*32 + m*16 + (lane&15))*128;
    #pragma unroll
    for (int nf = 0; nf < 4; ++nf)
        browb[nf] = 8192 + (wc*64 + nf*16 + (lane&15))*128;
    f32x4 acc[2][4];
    #pragma unroll
    for (int m = 0; m < 2; ++m)
        #pragma unroll
        for (int nf = 0; nf < 4; ++nf) acc[m][nf] = (f32x4){0.f,0.f,0.f,0.f};

    for (int kt = 0; kt < 3; ++kt) {
        __syncthreads();
        #pragma unroll
        for (int s2 = 0; s2 < 6; ++s2)
            load_lds16(gsrc[s2] + gbase[s2] + kt*64, smem + (wid*6+s2)*1024);
        __syncthreads();
        bf16x8 a[2][2], b[4][2];
        #pragma unroll
        for (int kk = 0; kk < 2; ++kk) {
            int gof = ((kk*4 + lh) ^ l7) << 4;
            #pragma unroll
            for (int m = 0; m < 2; ++m)
                a[m][kk] = *(const bf16x8*)(smem + arowb[m] + gof);
            #pragma unroll
            for (int nf = 0; nf < 4; ++nf)
                b[nf][kk] = *(const bf16x8*)(smem + browb[nf] + gof);
        }
        #pragma unroll
        for (int kk = 0; kk < 2; ++kk)
            #pragma unroll
            for (int m = 0; m < 2; ++m)
                #pragma unroll
                for (int nf = 0; nf < 4; ++nf)
                    acc[m][nf] = __builtin_amdgcn_mfma_f32_16x16x32_bf16(
                        a[m][kk], b[nf][kk], acc[m][nf], 0, 0, 0);
    }
    #pragma unroll
    for (int m = 0; m < 2; ++m) {
        int rbase = tileM + wr*32 + m*16 + (lane>>4)*4;
        float4 cz = *(const float4*)&cb2[rbase];
        #pragma unroll
        for (int nf = 0; nf < 4; ++nf) {
            int col = tileN + wc*64 + nf*16 + (lane&15);
            int bn = col / PP, p = col % PP;
            float v0 = fmaxf(acc[m][nf][0] + cz.x, 0.f);
            float v1 = fmaxf(acc[m][nf][1] + cz.y, 0.f);
            float v2 = fmaxf(acc[m][nf][2] + cz.z, 0.f);
            float v3 = fmaxf(acc[m][nf][3] + cz.w, 0.f);
            ushort4 bv;
            bv.x = f2bu(v0); bv.y = f2bu(v1); bv.z = f2bu(v2); bv.w = f2bu(v3);
            if (tileM == 0) {
                *(ushort4*)&qb16[(size_t)col*64 + rbase] = bv;
            } else {
                int kv = (tileM == 128) ? 1 : 0;
                int py = p / WW, px = p % WW;
                int d = rbase - tileM;
                *(ushort4*)&kvpad[((size_t)(bn*2+kv)*KVPA + (py+1)*KVPW + px+1)*64 + d] = bv;
                if (kv == 1)
                    *(ushort4*)&xvb16[(size_t)col*64 + d] = bv;
            }
        }
    }
}

// K4a: MFMA conv3x3 64->64 on kvpad -> convb bf16 [bn2][p][64]
__global__ __launch_bounds__(256) void k_kvgemm(const __hip_bfloat16* __restrict__ wA,
        const __hip_bfloat16* __restrict__ kvpad, const float* __restrict__ kvb,
        __hip_bfloat16* __restrict__ convb) {
    __shared__ __align__(16) char smem[24576];
    int tid = threadIdx.x;
    int wid = tid >> 6, lane = tid & 63;
    int tileN = blockIdx.x * 128;
    int bn2 = tileN / PP, p0 = tileN % PP;
    int sgr = ((lane&7) ^ (lane>>3)) * 8;

    size_t gbase[6];
    #pragma unroll
    for (int s2 = 0; s2 < 6; ++s2) {
        int seg = wid*6 + s2;
        if (seg < 8) {
            int row = seg*8 + (lane>>3);
            gbase[s2] = (size_t)row*576 + sgr;
        } else {
            int p = p0 + (seg-8)*8 + (lane>>3);
            int py = p / WW, px = p % WW;
            gbase[s2] = ((size_t)bn2*KVPA + (py+1)*KVPW + px+1)*64 + sgr;
        }
    }
    int wr = wid >> 1, wc = wid & 1;
    int l7 = lane & 7, lh = lane >> 4;
    int arowb[2], browb[4];
    #pragma unroll
    for (int m = 0; m < 2; ++m)
        arowb[m] = (wr*32 + m*16 + (lane&15))*128;
    #pragma unroll
    for (int nf = 0; nf < 4; ++nf)
        browb[nf] = 8192 + (wc*64 + nf*16 + (lane&15))*128;

    f32x4 acc[2][4];
    #pragma unroll
    for (int m = 0; m < 2; ++m)
        #pragma unroll
        for (int nf = 0; nf < 4; ++nf) acc[m][nf] = (f32x4){0.f,0.f,0.f,0.f};

    for (int kt = 0; kt < 9; ++kt) {
        int dy = kt/3 - 1, dx = kt%3 - 1;
        int doff = dy*KVPW + dx;
        __syncthreads();
        #pragma unroll
        for (int s2 = 0; s2 < 6; ++s2) {
            int seg = wid*6 + s2;
            const __hip_bfloat16* g = (seg < 8) ? wA + gbase[s2] + kt*64
                                                : kvpad + gbase[s2] + (size_t)doff*64;
            load_lds16(g, smem + seg*1024);
        }
        __syncthreads();
        bf16x8 a[2][2], b[4][2];
        #pragma unroll
        for (int kk = 0; kk < 2; ++kk) {
            int gof = ((kk*4 + lh) ^ l7) << 4;
            #pragma unroll
            for (int m = 0; m < 2; ++m)
                a[m][kk] = *(const bf16x8*)(smem + arowb[m] + gof);
            #pragma unroll
            for (int nf = 0; nf < 4; ++nf)
                b[nf][kk] = *(const bf16x8*)(smem + browb[nf] + gof);
        }
        #pragma unroll
        for (int kk = 0; kk < 2; ++kk)
            #pragma unroll
            for (int m = 0; m < 2; ++m)
                #pragma unroll
                for (int nf = 0; nf < 4; ++nf)
                    acc[m][nf] = __builtin_amdgcn_mfma_f32_16x16x32_bf16(
                        a[m][kk], b[nf][kk], acc[m][nf], 0, 0, 0);
    }
    #pragma unroll
    for (int m = 0; m < 2; ++m) {
        int rbase = wr*32 + m*16 + (lane>>4)*4;
        float4 bz = *(const float4*)&kvb[rbase];
        #pragma unroll
        for (int nf = 0; nf < 4; ++nf) {
            int col = p0 + wc*64 + nf*16 + (lane&15);
            ushort4 cv;
            cv.x = f2bu(fmaxf(acc[m][nf][0] + bz.x, 0.f));
            cv.y = f2bu(fmaxf(acc[m][nf][1] + bz.y, 0.f));
            cv.z = f2bu(fmaxf(acc[m][nf][2] + bz.z, 0.f));
            cv.w = f2bu(fmaxf(acc[m][nf][3] + bz.w, 0.f));
            *(ushort4*)&convb[((size_t)bn2*PP + col)*64 + rbase] = cv;
        }
    }
}

// K4b: 3x3 avgpool on convb -> kbufb bf16 [bn][k][d], vbufT bf16 [bn][d][k]
__global__ __launch_bounds__(256) void k_pool(const __hip_bfloat16* __restrict__ convb,
        __hip_bfloat16* __restrict__ kbufb, __hip_bfloat16* __restrict__ vbufT) {
    int idx = blockIdx.x*256 + threadIdx.x;
    int dg = idx % 8; idx /= 8;
    int pp = idx % PK; idx /= PK;
    int bn2 = idx;                       // bn*2+kv
    int kv = bn2 & 1, bn = bn2 >> 1;
    int qy = pp / KHW, qx = pp % KHW;
    float s[8] = {0,0,0,0,0,0,0,0};
    const __hip_bfloat16* base = convb + (size_t)bn2*PP*64 + dg*8;
    #pragma unroll
    for (int sy = 0; sy < 3; ++sy)
        #pragma unroll
        for (int sx = 0; sx < 3; ++sx) {
            union { bf16x8 v; unsigned short h[8]; } c;
            c.v = *(const bf16x8*)(base + ((size_t)(qy*3+sy)*WW + qx*3+sx)*64);
            #pragma unroll
            for (int j = 0; j < 8; ++j) s[j] += bu2f(c.h[j]);
        }
    if (kv == 0) {
        union { ushort4 u[2]; unsigned short h[8]; } cv;
        #pragma unroll
        for (int j = 0; j < 8; ++j) cv.h[j] = f2bu(s[j] * (1.f/9.f));
        ushort4* dst = (ushort4*)(kbufb + ((size_t)bn*PK + pp)*64 + dg*8);
        dst[0] = cv.u[0]; dst[1] = cv.u[1];
    } else {
        #pragma unroll
        for (int j = 0; j < 8; ++j)
            vbufT[((size_t)bn*64 + dg*8 + j)*PK + pp] = __float2bfloat16(s[j]*(1.f/81.f));
    }
}

// K5: MFMA leave-one-out sigmoid attention.
__global__ __launch_bounds__(256) void k_attn3(const __hip_bfloat16* __restrict__ qb16,
        const __hip_bfloat16* __restrict__ kbufb, const __hip_bfloat16* __restrict__ vbufT,
        float* __restrict__ attnp) {
    __shared__ __align__(16) char smem[32768];
    char* Qs = smem;
    char* Ks = smem + 8192;
    char* Vs = smem + 16384;
    char* Ps = smem + 24576;
    int tid = threadIdx.x;
    int wid = tid >> 6, lane = tid & 63;
    int bid = blockIdx.x;
    int ks = bid & 1; bid >>= 1;
    int qt = bid % 36; int bn = bid / 36;
    int b = bn / NVIEW, n = bn % NVIEW;
    int p0 = qt*64;

    {
        const char* gq = (const char*)(qb16 + ((size_t)bn*PP + p0)*64);
        #pragma unroll
        for (int i = 0; i < 2; ++i) {
            int s = wid*2 + i;
            int lin = s*1024 + lane*16;
            int r = lin >> 7, c = (lin >> 4) & 7;
            int gof = (r<<7) + ((c ^ (r&7)) << 4);
            load_lds16(gq + gof, Qs + s*1024);
        }
    }
    int arow = wid*16 + (lane&15);
    int brow = lane&15;
    int gcol = lane>>4;
    int vrow = tid >> 2;
    int vc2 = (tid & 3) * 2;

    f32x4 oacc[4];
    #pragma unroll
    for (int i = 0; i < 4; ++i) oacc[i] = (f32x4){0,0,0,0};

    for (int mi = 0; mi < NVIEW-1; ++mi) {
        int m = mi + (mi >= n ? 1 : 0);
        int bnk = b*NVIEW + m;
        const char* gk = (const char*)(kbufb + (size_t)bnk*PK*64);
        const __hip_bfloat16* gv = vbufT + (size_t)bnk*64*PK;
        for (int kc = ks*2; kc < ks*2+2; ++kc) {
            __syncthreads();
            #pragma unroll
            for (int i = 0; i < 2; ++i) {
                int s = wid*2 + i;
                int lin = s*1024 + lane*16;
                int r = lin >> 7, c = (lin >> 4) & 7;
                int gof = (r<<7) + ((c ^ (r&7)) << 4);
                load_lds16(gk + (size_t)kc*8192 + gof, Ks + s*1024);
            }
            {
                const __hip_bfloat16* src = gv + vrow*PK + kc*64 + vc2*8;
                bf16x8 v0 = *(const bf16x8*)src;
                bf16x8 v1 = *(const bf16x8*)(src+8);
                *(bf16x8*)(Vs + vrow*128 + ((vc2 ^ (vrow&7))<<4)) = v0;
                *(bf16x8*)(Vs + vrow*128 + (((vc2+1) ^ (vrow&7))<<4)) = v1;
            }
            __syncthreads();
            f32x4 sacc[4];
            #pragma unroll
            for (int i = 0; i < 4; ++i) sacc[i] = (f32x4){0,0,0,0};
            #pragma unroll
            for (int kk = 0; kk < 2; ++kk) {
                int g = kk*4 + gcol;
                bf16x8 af = *(const bf16x8*)(Ks + arow*128 + ((g ^ (arow&7))<<4));
                #pragma unroll
                for (int nf = 0; nf < 4; ++nf) {
                    int q = nf*16 + brow;
                    bf16x8 bq = *(const bf16x8*)(Qs + q*128 + ((g ^ (q&7))<<4));
                    sacc[nf] = __builtin_amdgcn_mfma_f32_16x16x32_bf16(af, bq, sacc[nf], 0,0,0);
                }
            }
            {
                int kbase = wid*16 + gcol*4;
                #pragma unroll
                for (int nf = 0; nf < 4; ++nf) {
                    int q = nf*16 + brow;
                    ushort4 pu;
                    float e0 = __expf(-sacc[nf][0]*0.125f);
                    float e1 = __expf(-sacc[nf][1]*0.125f);
                    float e2 = __expf(-sacc[nf][2]*0.125f);
                    float e3 = __expf(-sacc[nf][3]*0.125f);
                    pu.x = f2bu(__builtin_amdgcn_rcpf(1.f+e0));
                    pu.y = f2bu(__builtin_amdgcn_rcpf(1.f+e1));
                    pu.z = f2bu(__builtin_amdgcn_rcpf(1.f+e2));
                    pu.w = f2bu(__builtin_amdgcn_rcpf(1.f+e3));
                    *(ushort4*)(Ps + q*128 + (((kbase>>3) ^ (q&7))<<4) + (kbase&7)*2) = pu;
                }
            }
            __syncthreads();
            #pragma unroll
            for (int kk = 0; kk < 2; ++kk) {
                int g = kk*4 + gcol;
                int qr = wid*16 + brow;
                bf16x8 pf = *(const bf16x8*)(Ps + qr*128 + ((g ^ (qr&7))<<4));
                #pragma unroll
                for (int nf = 0; nf < 4; ++nf) {
                    int d = nf*16 + brow;
                    bf16x8 vf = *(const bf16x8*)(Vs + d*128 + ((g ^ (d&7))<<4));
                    oacc[nf] = __builtin_amdgcn_mfma_f32_16x16x32_bf16(pf, vf, oacc[nf], 0,0,0);
                }
            }
        }
    }
    float* ab = attnp + (size_t)ks*SZ_ATTNP + ((size_t)bn*PP + p0)*64;
    #pragma unroll
    for (int nf = 0; nf < 4; ++nf) {
        #pragma unroll
        for (int r = 0; r < 4; ++r) {
            int q = wid*16 + gcol*4 + r;
            int d = nf*16 + brow;
            ab[(size_t)q*64 + d] = oacc[nf][r];
        }
    }
}

// K6: MFMA epilogue: out = relu(W2 relu(W1 relu(attn0+attn1 + sc*xv) + b1) + b2)
__global__ __launch_bounds__(256) void k_out2(const float* __restrict__ attnp,
        const __hip_bfloat16* __restrict__ xvb16, const float* __restrict__ scales,
        const __hip_bfloat16* __restrict__ w1sw, const __hip_bfloat16* __restrict__ w2sw,
        const float* __restrict__ b1, const float* __restrict__ b2,
        float* __restrict__ out) {
    __shared__ __align__(16) char smem[49152];
    char* W1s = smem;
    char* W2s = smem + 8192;
    char* Rs  = smem + 16384;
    char* Ts  = smem + 32768;
    int tid = threadIdx.x;
    int wid = tid >> 6, lane = tid & 63;
    int pix0 = blockIdx.x * 128;
    int bn = pix0 / PP;
    int pb = pix0 - bn*PP;
    float sc = scales[bn % NVIEW];

    #pragma unroll
    for (int i = 0; i < 4; ++i) {
        int seg = wid*4 + i;
        const char* src = (seg < 8) ? (const char*)w1sw + seg*1024
                                    : (const char*)w2sw + (seg-8)*1024;
        load_lds16(src + lane*16, smem + seg*1024);
    }
    {
        int p = tid >> 1, d0 = (tid & 1) * 32;
        int P = pix0 + p;
        const float* a0 = attnp + (size_t)P*64 + d0;
        const float* a1 = a0 + SZ_ATTNP;
        const __hip_bfloat16* xv = xvb16 + (size_t)P*64 + d0;
        #pragma unroll
        for (int j = 0; j < 4; ++j) {
            float4 u0 = *(const float4*)(a0 + j*8);
            float4 u1 = *(const float4*)(a0 + j*8 + 4);
            float4 v0 = *(const float4*)(a1 + j*8);
            float4 v1 = *(const float4*)(a1 + j*8 + 4);
            union { bf16x8 v; unsigned short h[8]; } xu;
            xu.v = *(const bf16x8*)(xv + j*8);
            union { bf16x8 v; unsigned short h[8]; } rv;
            rv.h[0] = f2bu(fmaxf(u0.x + v0.x + sc*bu2f(xu.h[0]), 0.f));
            rv.h[1] = f2bu(fmaxf(u0.y + v0.y + sc*bu2f(xu.h[1]), 0.f));
            rv.h[2] = f2bu(fmaxf(u0.z + v0.z + sc*bu2f(xu.h[2]), 0.f));
            rv.h[3] = f2bu(fmaxf(u0.w + v0.w + sc*bu2f(xu.h[3]), 0.f));
            rv.h[4] = f2bu(fmaxf(u1.x + v1.x + sc*bu2f(xu.h[4]), 0.f));
            rv.h[5] = f2bu(fmaxf(u1.y + v1.y + sc*bu2f(xu.h[5]), 0.f));
            rv.h[6] = f2bu(fmaxf(u1.z + v1.z + sc*bu2f(xu.h[6]), 0.f));
            rv.h[7] = f2bu(fmaxf(u1.w + v1.w + sc*bu2f(xu.h[7]), 0.f));
            int g = (d0 >> 3) + j;
            *(bf16x8*)(Rs + p*128 + ((g ^ (p&7)) << 4)) = rv.v;
        }
    }
    __syncthreads();

    int wr = wid >> 1, wc = wid & 1;
    int rrow = lane & 15, gcol = lane >> 4;
    f32x4 acc1[2][4];
    #pragma unroll
    for (int m = 0; m < 2; ++m)
        #pragma unroll
        for (int nf = 0; nf < 4; ++nf) acc1[m][nf] = (f32x4){0,0,0,0};
    #pragma unroll
    for (int kk = 0; kk < 2; ++kk) {
        int g = kk*4 + gcol;
        #pragma unroll
        for (int m = 0; m < 2; ++m) {
            int oc = wr*32 + m*16 + rrow;
            bf16x8 af = *(const bf16x8*)(W1s + oc*128 + ((g ^ (oc&7)) << 4));
            #pragma unroll
            for (int nf = 0; nf < 4; ++nf) {
                int px = wc*64 + nf*16 + rrow;
                bf16x8 bf = *(const bf16x8*)(Rs + px*128 + ((g ^ (px&7)) << 4));
                acc1[m][nf] = __builtin_amdgcn_mfma_f32_16x16x32_bf16(af, bf, acc1[m][nf], 0,0,0);
            }
        }
    }
    #pragma unroll
    for (int m = 0; m < 2; ++m) {
        int oc0 = wr*32 + m*16 + gcol*4;
        float4 bz = *(const float4*)&b1[oc0];
        #pragma unroll
        for (int nf = 0; nf < 4; ++nf) {
            int px = wc*64 + nf*16 + rrow;
            ushort4 tv;
            tv.x = f2bu(fmaxf(acc1[m][nf][0] + bz.x, 0.f));
            tv.y = f2bu(fmaxf(acc1[m][nf][1] + bz.y, 0.f));
            tv.z = f2bu(fmaxf(acc1[m][nf][2] + bz.z, 0.f));
            tv.w = f2bu(fmaxf(acc1[m][nf][3] + bz.w, 0.f));
            *(ushort4*)(Ts + px*128 + (((oc0>>3) ^ (px&7)) << 4) + (oc0&7)*2) = tv;
        }
    }
    __syncthreads();
    f32x4 acc2[2][4];
    #pragma unroll
    for (int m = 0; m < 2; ++m)
        #pragma unroll
        for (int nf = 0; nf < 4; ++nf) acc2[m][nf] = (f32x4){0,0,0,0};
    #pragma unroll
    for (int kk = 0; kk < 2; ++kk) {
        int g = kk*4 + gcol;
        #pragma unroll
        for (int m = 0; m < 2; ++m) {
            int oc = wr*32 + m*16 + rrow;
            bf16x8 af = *(const bf16x8*)(W2s + oc*128 + ((g ^ (oc&7)) << 4));
            #pragma unroll
            for (int nf = 0; nf < 4; ++nf) {
                int px = wc*64 + nf*16 + rrow;
                bf16x8 bf = *(const bf16x8*)(Ts + px*128 + ((g ^ (px&7)) << 4));
                acc2[m][nf] = __builtin_amdgcn_mfma_f32_16x16x32_bf16(af, bf, acc2[m][nf], 0,0,0);
            }
        }
    }
    #pragma unroll
    for (int m = 0; m < 2; ++m) {
        int oc0 = wr*32 + m*16 + gcol*4;
        float4 bz = *(const float4*)&b2[oc0];
        #pragma unroll
        for (int nf = 0; nf < 4; ++nf) {
            int px = wc*64 + nf*16 + rrow;
            float* dst = out + ((size_t)bn*64 + oc0)*PP + pb + px;
            dst[0*PP] = fmaxf(acc2[m][nf][0] + bz.x, 0.f);
            dst[1*PP] = fmaxf(acc2[m][nf][1] + bz.y, 0.f);
            dst[2*PP] = fmaxf(acc2[m][nf][2] + bz.z, 0.f);
            dst[3*PP] = fmaxf(acc2[m][nf][3] + bz.w, 0.f);
        }
    }
}

extern "C" void kernel_launch(void* const* d_in, const int* in_sizes, int n_in,
                              void* d_out, int out_size, void* d_ws, size_t ws_size,
                              hipStream_t stream) {
    (void)in_sizes; (void)n_in; (void)out_size; (void)ws_size;
    const float* x      = (const float*)d_in[0];
    const float* pa_w1  = (const float*)d_in[1];
    const float* pa_b1  = (const float*)d_in[2];
    const float* pa_w2  = (const float*)d_in[3];
    const float* pa_b2  = (const float*)d_in[4];
    const float* pa_w3  = (const float*)d_in[5];
    const float* pa_b3  = (const float*)d_in[6];
    const float* pa_cw1 = (const float*)d_in[7];
    const float* pa_cb1 = (const float*)d_in[8];
    const float* pa_cw2 = (const float*)d_in[9];
    const float* pa_cb2 = (const float*)d_in[10];
    const float* kv_w   = (const float*)d_in[11];
    const float* kv_b   = (const float*)d_in[12];
    const float* out_w1 = (const float*)d_in[13];
    const float* out_b1 = (const float*)d_in[14];
    const float* out_w2 = (const float*)d_in[15];
    const float* out_b2 = (const float*)d_in[16];
    const float* scales = (const float*)d_in[17];
    float* out = (float*)d_out;
    float* ws  = (float*)d_ws;

    __hip_bfloat16* weffb = (__hip_bfloat16*)(ws + OFF_WEFFB);
    float* beff = ws + OFF_BEFF;
    __hip_bfloat16* cw2b  = (__hip_bfloat16*)(ws + OFF_CW2B);
    __hip_bfloat16* wkvb  = (__hip_bfloat16*)(ws + OFF_WKVB);
    __hip_bfloat16* padxT = (__hip_bfloat16*)(ws + OFF_PADXT);
    __hip_bfloat16* qb16  = (__hip_bfloat16*)(ws + OFF_QB16);
    __hip_bfloat16* kbufb = (__hip_bfloat16*)(ws + OFF_KB16);
    __hip_bfloat16* vbufT = (__hip_bfloat16*)(ws + OFF_VB16T);
    __hip_bfloat16* kvpad = (__hip_bfloat16*)(ws + OFF_KVPAD);
    __hip_bfloat16* convb = (__hip_bfloat16*)(ws + OFF_CONVB);
    __hip_bfloat16* w1sw  = (__hip_bfloat16*)(ws + OFF_W1SW);
    __hip_bfloat16* w2sw  = (__hip_bfloat16*)(ws + OFF_W2SW);
    __hip_bfloat16* hidbt = (__hip_bfloat16*)(ws + OFF_ATTNP);  // alias (pre-attn)
    float* attnp = ws + OFF_ATTNP;
    __hip_bfloat16* xvb16 = (__hip_bfloat16*)(ws + OFF_XVB16);

    k_fold<<<3*OC, CIN*9, 0, stream>>>(pa_cw1, pa_cb1, pa_w1, pa_b1,
                                       pa_w2, pa_b2, pa_w3, pa_b3, weffb, beff);
    k_wkvb<<<(64*576+255)/256, 256, 0, stream>>>(kv_w, wkvb);
    k_wcvt<<<(OC*OC+255)/256, 256, 0, stream>>>(pa_cw2, cw2b);
    k_wout<<<(2*4096+255)/256, 256, 0, stream>>>(out_w1, out_w2, w1sw, w2sw);
    k_padxT<<<(BN*PADA+255)/256, 256, 0, stream>>>(x, padxT);
    k_zero<<<(BN*2*KVPA*64/8)/256, 256, 0, stream>>>(kvpad);
    k_gemm1<<<dim3(NTOT/128, 3), 256, 0, stream>>>(weffb, padxT, beff, hidbt);
    k_gemm2<<<dim3(NTOT/128, 3), 256, 0, stream>>>(cw2b, hidbt, pa_cb2, xvb16, qb16, kvpad);
    k_kvgemm<<<BN*2*PP/128, 256, 0, stream>>>(wkvb, kvpad, kv_b, convb);
    k_pool<<<BN*2*PK*8/256, 256, 0, stream>>>(convb, kbufb, vbufT);
    k_attn3<<<BN*36*2, 256, 0, stream>>>(qb16, kbufb, vbufT, attnp);
    k_out2<<<NTOT/128, 256, 0, stream>>>(attnp, xvb16, scales, w1sw, w2sw,
                                         out_b1, out_b2, out);
}